// Round 8
// baseline (651.314 us; speedup 1.0000x reference)
//
#include <hip/hip_runtime.h>
#include <hip/hip_bf16.h>

#define NN 102400      // B*T*NODES
#define DD 64
#define EE 1638400
#define L1C 96
#define L2C 64
#define TT 32
#define NODESC 400
#define BB 8
#define SS 3200        // B*NODES
#define G4 256         // 4*D

#define NBUK 400       // coarse buckets (node >> 8), NN = 400*256 exactly
#define BCAP 5120      // slots per bucket (mean 4096, sd 64 -> +16 sigma)
#define PCHUNK 8192
#define NPART (EE / PCHUNK)   // 200

// ---------------- workspace layout (floats) ----------------
// [0, 26,214,400): ent | a1 | g1  -> all dead before xg overwrites the region
#define OFF_ENT  ((size_t)0)          // NBUK*BCAP int2 = 4,096,000 floats
#define OFF_A1   ((size_t)4096000)    // NN*64 -> ends 10,649,600
#define OFF_G1   ((size_t)10649600)   // NN*96 -> ends 20,480,000
#define OFF_XG   ((size_t)0)          // NN*256 = 26,214,400
#define OFF_ENT2 ((size_t)26214400)   // staging, 4,096,000 (dead before h2 written)
#define OFF_H2   ((size_t)26214400)   // NN*64 -> ends 32,768,000
#define OFF_G2   ((size_t)32768000)   // NN*64 -> ends 39,321,600
#define OFF_GCUR ((size_t)39321600)   // 400 cursors padded x16 ints = 6400
#define OFF_DIS  ((size_t)39328000)   // NN -> ends 39,430,400
#define OFF_RNG  ((size_t)39430400)   // NN int2 -> ends 39,635,200
#define OFF_HL   ((size_t)39635200)   // SS*64 -> ends 39,840,000
#define OFF_ST   ((size_t)39840000)   // 256 -> total 39,840,256 floats (159.4 MB)

__device__ __forceinline__ void fma4(float4& a, float s, const float4& w) {
    a.x = fmaf(s, w.x, a.x); a.y = fmaf(s, w.y, a.y);
    a.z = fmaf(s, w.z, a.z); a.w = fmaf(s, w.w, a.w);
}
__device__ __forceinline__ float dot4(const float4 a, const float4 b, float acc) {
    acc = fmaf(a.x, b.x, acc); acc = fmaf(a.y, b.y, acc);
    acc = fmaf(a.z, b.z, acc); acc = fmaf(a.w, b.w, acc);
    return acc;
}
__device__ __forceinline__ float rcp_f(float x) { return __builtin_amdgcn_rcpf(x); }
__device__ __forceinline__ float sigm_f(float x) {
    x = fminf(fmaxf(x, -30.f), 30.f);
    return rcp_f(1.f + __expf(-x));
}
__device__ __forceinline__ float tanh_f(float x) {
    x = fminf(fmaxf(x, -15.f), 15.f);
    float e = __expf(2.f * x);
    return (e - 1.f) * rcp_f(e + 1.f);
}

// ---------------- init: zero bucket cursors + stats ----------------
__global__ void init_zero(int* gcur, float* st) {
    int idx = blockIdx.x * 256 + threadIdx.x;
    if (idx < NBUK * 16) gcur[idx] = 0;
    if (blockIdx.x == 0 && threadIdx.x < 128) st[threadIdx.x] = 0.f;
}

// ---------------- normalization stats ----------------
__global__ __launch_bounds__(256) void col_sums(const float* __restrict__ x, float* __restrict__ st) {
    int c = threadIdx.x & 63;
    size_t i = (size_t)blockIdx.x * 256 + threadIdx.x;
    size_t stride = (size_t)gridDim.x * 256;
    float s = 0.f, q = 0.f;
    for (size_t e = i; e < (size_t)NN * 64; e += stride) {
        float v = x[e]; s += v; q = fmaf(v, v, q);
    }
    __shared__ float ls[128];
    if (threadIdx.x < 128) ls[threadIdx.x] = 0.f;
    __syncthreads();
    atomicAdd(&ls[c], s); atomicAdd(&ls[64 + c], q);
    __syncthreads();
    if (threadIdx.x < 128) atomicAdd(&st[threadIdx.x], ls[threadIdx.x]);
}

__global__ void finalize_stats(float* st) {
    int c = threadIdx.x;
    if (c < 64) {
        float s = st[c], q = st[64 + c];
        float mean = s / (float)NN;
        float var = (q - s * s / (float)NN) / (float)(NN - 1);
        st[128 + c] = mean;
        st[192 + c] = rsqrtf(fmaxf(var, 1e-20f));
    }
}

// ---------------- pass 1: coarse bucket partition (contiguous block-local runs) ----------------
// Entry staging format: meta = src | (dst&255)<<24 (src < 2^17), w = |ea| bits.
__global__ __launch_bounds__(256) void part_kernel(const int* __restrict__ ei, const float* __restrict__ ea,
                                                   int* __restrict__ gcur, int2* __restrict__ ent2) {
    __shared__ int lhist[NBUK];
    __shared__ int lbase[NBUK];
    const int tid = threadIdx.x;
    const int e0 = blockIdx.x * PCHUNK;
    for (int i = tid; i < NBUK; i += 256) lhist[i] = 0;
    __syncthreads();
    #pragma unroll 4
    for (int i = 0; i < PCHUNK / 256; ++i) {
        int d = ei[EE + e0 + i * 256 + tid];
        atomicAdd(&lhist[d >> 8], 1);
    }
    __syncthreads();
    // reserve one contiguous range per bucket (gcur padded: 1 counter / 64B line)
    for (int i = tid; i < NBUK; i += 256) {
        lbase[i] = atomicAdd(&gcur[i * 16], lhist[i]);
        lhist[i] = 0;
    }
    __syncthreads();
    for (int i = 0; i < PCHUNK / 256; ++i) {
        int e = e0 + i * 256 + tid;
        int d = ei[EE + e];
        int s = ei[e];
        float w = fabsf(ea[2 * (size_t)e]);
        int b = d >> 8;
        int local = atomicAdd(&lhist[b], 1);
        int pos = lbase[b] + local;
        if (pos < BCAP)
            ent2[(size_t)b * BCAP + pos] = make_int2(s | ((d & 255) << 24), __float_as_int(w));
    }
}

// ---------------- pass 2: per-bucket counting sort in LDS + rng + dis ----------------
__global__ __launch_bounds__(256) void bucket_csr(const int2* __restrict__ ent2, const int* __restrict__ gcur,
                                                  int2* __restrict__ ent, int2* __restrict__ rng,
                                                  float* __restrict__ dis) {
    __shared__ int nhist[256];
    __shared__ int scn[256];
    __shared__ float wsum[256];
    __shared__ int pcur[256];
    const int tid = threadIdx.x;
    const int b = blockIdx.x;
    const int base = b * BCAP;
    int cnt = gcur[b * 16];
    if (cnt > BCAP) cnt = BCAP;
    nhist[tid] = 0;
    wsum[tid] = 0.f;
    __syncthreads();
    for (int e = tid; e < cnt; e += 256) {
        int2 en = ent2[base + e];
        int dl = ((unsigned)en.x) >> 24;
        atomicAdd(&nhist[dl], 1);
        atomicAdd(&wsum[dl], __int_as_float(en.y));
    }
    __syncthreads();
    int c = nhist[tid];
    scn[tid] = c;
    __syncthreads();
    for (int d = 1; d < 256; d <<= 1) {
        int t = (tid >= d) ? scn[tid - d] : 0;
        __syncthreads();
        scn[tid] += t;
        __syncthreads();
    }
    int ps = scn[tid] - c;                       // exclusive prefix within bucket
    rng[b * 256 + tid] = make_int2(base + ps, base + ps + c);
    dis[b * 256 + tid] = rsqrtf(1.f + wsum[tid]); // self-loop weight 1 folded in
    pcur[tid] = ps;
    __syncthreads();
    for (int e = tid; e < cnt; e += 256) {
        int2 en = ent2[base + e];
        int dl = ((unsigned)en.x) >> 24;
        int local = atomicAdd(&pcur[dl], 1);
        ent[base + local] = make_int2(en.x & 0xFFFFFF, en.y);
    }
}

// ---------------- tiled f32 GEMM ----------------
template<int K, int NC, int MB, int THREADS, bool PRELU, bool TRANSW, bool XGOUT>
__global__ __launch_bounds__(THREADS) void gemm_tiled(
    const float* __restrict__ A, const float* __restrict__ Wm,
    const float* __restrict__ bin, const float* __restrict__ bo1, const float* __restrict__ bo2,
    float* __restrict__ Cm, int ldC)
{
    __shared__ float As[MB * K];
    __shared__ float Ws[K * NC];
    const int cb0 = TRANSW ? ((int)blockIdx.y * NC) : 0;   // xg column-half select

    if (!TRANSW) {
        for (int i = threadIdx.x; i < K * NC / 4; i += THREADS)
            ((float4*)Ws)[i] = ((const float4*)Wm)[i];
    } else {
        for (int i = threadIdx.x; i < NC * (K / 4); i += THREADS) {
            int g = i / (K / 4); int d = (i % (K / 4)) * 4;
            float4 v = *(const float4*)(Wm + (size_t)(cb0 + g) * K + d);
            Ws[(d + 0) * NC + g] = v.x; Ws[(d + 1) * NC + g] = v.y;
            Ws[(d + 2) * NC + g] = v.z; Ws[(d + 3) * NC + g] = v.w;
        }
    }
    size_t row0 = (size_t)blockIdx.x * MB;
    for (int i = threadIdx.x; i < MB * (K / 4); i += THREADS) {
        int r = i / (K / 4); int c = (i % (K / 4)) * 4;
        float4 a = *(const float4*)(A + (row0 + r) * K + c);
        if (PRELU) {
            a.x = fmaxf(a.x + bin[c + 0], 0.f); a.y = fmaxf(a.y + bin[c + 1], 0.f);
            a.z = fmaxf(a.z + bin[c + 2], 0.f); a.w = fmaxf(a.w + bin[c + 3], 0.f);
        }
        ((float4*)As)[i] = a;
    }
    __syncthreads();

    constexpr int NCT = NC / 4;
    int tc = threadIdx.x % NCT;
    int tr = threadIdx.x / NCT;
    int r = tr * 4;
    float4 acc[4];
    acc[0] = acc[1] = acc[2] = acc[3] = make_float4(0.f, 0.f, 0.f, 0.f);

    #pragma unroll 8
    for (int d4 = 0; d4 < K / 4; ++d4) {
        float4 w0 = ((const float4*)Ws)[(4 * d4 + 0) * NCT + tc];
        float4 w1 = ((const float4*)Ws)[(4 * d4 + 1) * NCT + tc];
        float4 w2 = ((const float4*)Ws)[(4 * d4 + 2) * NCT + tc];
        float4 w3 = ((const float4*)Ws)[(4 * d4 + 3) * NCT + tc];
        #pragma unroll
        for (int i = 0; i < 4; ++i) {
            float4 av = ((const float4*)As)[(r + i) * (K / 4) + d4];
            fma4(acc[i], av.x, w0); fma4(acc[i], av.y, w1);
            fma4(acc[i], av.z, w2); fma4(acc[i], av.w, w3);
        }
    }

    if (!XGOUT) {
        #pragma unroll
        for (int i = 0; i < 4; ++i) {
            size_t row = row0 + r + i;
            *(float4*)(Cm + row * ldC + tc * 4) = acc[i];
        }
    } else {
        int cb = cb0 + tc * 4;
        float4 bs;
        bs.x = bo1[cb + 0] + bo2[cb + 0]; bs.y = bo1[cb + 1] + bo2[cb + 1];
        bs.z = bo1[cb + 2] + bo2[cb + 2]; bs.w = bo1[cb + 3] + bo2[cb + 3];
        #pragma unroll
        for (int i = 0; i < 4; ++i) {
            int n = (int)row0 + r + i;                      // n = b*T*NODES + t*NODES + node
            int b_ = n / (TT * NODESC);
            int rem = n - b_ * (TT * NODESC);
            int t = rem / NODESC;
            int node = rem - t * NODESC;
            int orow = (b_ * NODESC + node) * TT + t;       // seq-major, time inner
            float4 o = acc[i];
            o.x += bs.x; o.y += bs.y; o.z += bs.z; o.w += bs.w;
            *(float4*)(Cm + (size_t)orow * ldC + cb) = o;
        }
    }
}

// ---------------- GCN aggregation: gather over packed CSR (rng int2 ranges) ----------------
// g[n] = dis[n] * ( dis[n]*h[n] + sum_e w_e*dis[src_e]*h[src_e] )
template<int C4, bool NORM>
__global__ __launch_bounds__(256) void gcn_gather(const float* __restrict__ h, const int2* __restrict__ rng,
                                                  const int2* __restrict__ ent, const float* __restrict__ dis,
                                                  const float* __restrict__ st, float* __restrict__ g) {
    unsigned int idx = blockIdx.x * 256 + threadIdx.x;
    unsigned int n = idx / C4, q = idx % C4;
    float4 mean4, istd4;
    if (NORM) {
        mean4 = ((const float4*)(st + 128))[q];
        istd4 = ((const float4*)(st + 192))[q];
    }
    float dn = dis[n];
    float4 acc = ((const float4*)h)[(size_t)n * C4 + q];
    if (NORM) {
        acc.x = (acc.x - mean4.x) * istd4.x; acc.y = (acc.y - mean4.y) * istd4.y;
        acc.z = (acc.z - mean4.z) * istd4.z; acc.w = (acc.w - mean4.w) * istd4.w;
    }
    acc.x *= dn; acc.y *= dn; acc.z *= dn; acc.w *= dn;
    int2 r = rng[n];
    for (int e = r.x; e < r.y; ++e) {
        int2 en = ent[e];
        float w = __int_as_float(en.y) * dis[en.x];
        float4 v = ((const float4*)h)[(size_t)en.x * C4 + q];
        if (NORM) {
            v.x = (v.x - mean4.x) * istd4.x; v.y = (v.y - mean4.y) * istd4.y;
            v.z = (v.z - mean4.z) * istd4.z; v.w = (v.w - mean4.w) * istd4.w;
        }
        fma4(acc, w, v);
    }
    acc.x *= dn; acc.y *= dn; acc.z *= dn; acc.w *= dn;
    ((float4*)g)[(size_t)n * C4 + q] = acc;
}

// ---------------- LSTM (recurrent part; xg precomputed) ----------------
// 1024 threads = 16 waves; 8 seqs/block (grid 400).
// R4-R7 lesson: the allocator refuses to keep loop-invariant global-loaded
// weight arrays (>=32 floats/thread) in VGPRs across a barrier-laden loop.
// So: w_hh staged in LDS (quarters 0-2, 48 KB; lane-consecutive float4 layout
// for the measured-fast LDS access pattern), quarter 3 kept as a single float4
// in registers (4 VGPRs -- small enough to survive). Thread tid owns
// (row = tid>>2, k-quarter = tid&3): 16 weights, 32 broadcast h-reads and 128
// FMA per t-step, pair reduction via 2x shfl_xor. Activation phase: threads
// 0..511 own (seq, unit); xg gate inputs software-pipelined one step ahead.
__global__ __launch_bounds__(1024, 4) void lstm_kernel(const float* __restrict__ xg, const float* __restrict__ whh,
                                                       float* __restrict__ hlast) {
    __shared__ float4 wl[3][1024];     // 48 KB: wl[i][tid] = w_hh float4 (tid*4 + i)
    __shared__ float hs[8][64];        // 2 KB
    __shared__ float gp[8][256];       // 8 KB
    const int tid = threadIdx.x;       // 0..1023
    const int row = tid >> 2;          // gate row 0..255
    const int quarter = tid & 3;       // k-quarter 0..3
    const float4* whh4 = (const float4*)whh;
    wl[0][tid] = whh4[4 * tid + 0];
    wl[1][tid] = whh4[4 * tid + 1];
    wl[2][tid] = whh4[4 * tid + 2];
    const float4 wv3 = whh4[4 * tid + 3];
    const int qa = tid >> 6;           // activation: seq 0..7 (valid tid<512)
    const int ja = tid & 63;           // activation: hidden unit
    float c_reg = 0.f, hn = 0.f;
    if (tid < 512) ((float*)hs)[tid] = 0.f;     // hs = 512 floats exactly
    const float* xa = xg + (size_t)blockIdx.x * 8 * TT * G4 + (size_t)(qa & 7) * TT * G4 + ja;
    float xi = 0.f, xf = 0.f, xgv = 0.f, xo = 0.f;
    if (tid < 512) { xi = xa[0]; xf = xa[64]; xgv = xa[128]; xo = xa[192]; }
    __syncthreads();
    for (int t = 0; t < TT; ++t) {
        // prefetch next step's gate inputs (activation threads only)
        float ni = 0.f, nf = 0.f, ng = 0.f, no = 0.f;
        if (tid < 512) {
            const int tn = (t + 1 < TT) ? t + 1 : t;
            const float* xan = xa + tn * G4;
            ni = xan[0]; nf = xan[64]; ng = xan[128]; no = xan[192];
        }
        const float4 wv0 = wl[0][tid];
        const float4 wv1 = wl[1][tid];
        const float4 wv2 = wl[2][tid];
        #pragma unroll
        for (int q = 0; q < 8; ++q) {
            const float4* hq = (const float4*)(hs[q]) + quarter * 4;
            float4 h0 = hq[0], h1 = hq[1], h2 = hq[2], h3 = hq[3];
            float p = dot4(h3, wv3, dot4(h2, wv2, dot4(h1, wv1, dot4(h0, wv0, 0.f))));
            p += __shfl_xor(p, 1);
            p += __shfl_xor(p, 2);
            if (quarter == 0) gp[q][row] = p;
        }
        __syncthreads();                  // gp ready; hs reads of this step done
        if (tid < 512) {
            float gi = gp[qa][ja]       + xi;
            float gf = gp[qa][64 + ja]  + xf;
            float gg = gp[qa][128 + ja] + xgv;
            float go = gp[qa][192 + ja] + xo;
            c_reg = sigm_f(gf) * c_reg + sigm_f(gi) * tanh_f(gg);
            hn = sigm_f(go) * tanh_f(c_reg);
            hs[qa][ja] = hn;
        }
        __syncthreads();                  // hs ready for next step
        xi = ni; xf = nf; xgv = ng; xo = no;
    }
    if (tid < 512)
        hlast[((size_t)blockIdx.x * 8 + qa) * 64 + ja] = hn;
}

// ---------------- FC head + softmax ----------------
__global__ __launch_bounds__(128) void head_kernel(const float* __restrict__ hl,
                                                   const float* __restrict__ w1, const float* __restrict__ b1,
                                                   const float* __restrict__ w2, const float* __restrict__ b2,
                                                   float* __restrict__ out) {
    __shared__ float hrow[64];
    __shared__ float a1[128];
    __shared__ float lg[3];
    int s = blockIdx.x, tid = threadIdx.x;
    if (tid < 64) hrow[tid] = hl[(size_t)s * 64 + tid];
    __syncthreads();
    {
        const float4* wr = (const float4*)(w1 + (size_t)tid * 64);
        const float4* hq = (const float4*)hrow;
        float4 acc = make_float4(0.f, 0.f, 0.f, 0.f);
        #pragma unroll
        for (int k = 0; k < 16; ++k) {
            float4 wv = wr[k]; float4 hv = hq[k];
            acc.x = fmaf(wv.x, hv.x, acc.x); acc.y = fmaf(wv.y, hv.y, acc.y);
            acc.z = fmaf(wv.z, hv.z, acc.z); acc.w = fmaf(wv.w, hv.w, acc.w);
        }
        a1[tid] = fmaxf((acc.x + acc.y) + (acc.z + acc.w) + b1[tid], 0.f);
    }
    __syncthreads();
    if (tid < 3) {
        const float4* wr = (const float4*)(w2 + (size_t)tid * 128);
        const float4* aq = (const float4*)a1;
        float4 acc = make_float4(0.f, 0.f, 0.f, 0.f);
        #pragma unroll
        for (int k = 0; k < 32; ++k) {
            float4 wv = wr[k]; float4 av = aq[k];
            acc.x = fmaf(wv.x, av.x, acc.x); acc.y = fmaf(wv.y, av.y, acc.y);
            acc.z = fmaf(wv.z, av.z, acc.z); acc.w = fmaf(wv.w, av.w, acc.w);
        }
        lg[tid] = (acc.x + acc.y) + (acc.z + acc.w) + b2[tid];
    }
    __syncthreads();
    if (tid == 0) {
        float m = fmaxf(lg[0], fmaxf(lg[1], lg[2]));
        float e0 = __expf(lg[0] - m), e1 = __expf(lg[1] - m), e2 = __expf(lg[2] - m);
        float inv = 1.f / (e0 + e1 + e2);
        out[(size_t)s * 3 + 0] = e0 * inv;
        out[(size_t)s * 3 + 1] = e1 * inv;
        out[(size_t)s * 3 + 2] = e2 * inv;
    }
}

extern "C" void kernel_launch(void* const* d_in, const int* in_sizes, int n_in,
                              void* d_out, int out_size, void* d_ws, size_t ws_size,
                              hipStream_t stream) {
    (void)in_sizes; (void)n_in; (void)out_size; (void)ws_size;
    const float* x        = (const float*)d_in[0];
    const float* ea       = (const float*)d_in[1];
    const float* conv1_w  = (const float*)d_in[2];
    const float* conv1_b  = (const float*)d_in[3];
    const float* conv2_w  = (const float*)d_in[4];
    const float* conv2_b  = (const float*)d_in[5];
    const float* w_ih     = (const float*)d_in[6];
    const float* w_hh     = (const float*)d_in[7];
    const float* b_ih     = (const float*)d_in[8];
    const float* b_hh     = (const float*)d_in[9];
    const float* fc1_w    = (const float*)d_in[10];
    const float* fc1_b    = (const float*)d_in[11];
    const float* fc2_w    = (const float*)d_in[12];
    const float* fc2_b    = (const float*)d_in[13];
    const int*   ei       = (const int*)d_in[14];
    float* out = (float*)d_out;

    float* W    = (float*)d_ws;
    int2*  ent  = (int2*)(W + OFF_ENT);
    float* a1   = W + OFF_A1;
    float* g1   = W + OFF_G1;
    float* xg   = W + OFF_XG;
    int2*  ent2 = (int2*)(W + OFF_ENT2);
    float* h2   = W + OFF_H2;
    float* g2   = W + OFF_G2;
    int*   gcur = (int*)(W + OFF_GCUR);
    float* dis  = W + OFF_DIS;
    int2*  rng  = (int2*)(W + OFF_RNG);
    float* hl   = W + OFF_HL;
    float* st   = W + OFF_ST;

    // init + normalization stats (normalization itself fused into gather-1)
    init_zero<<<26, 256, 0, stream>>>(gcur, st);
    col_sums<<<1024, 256, 0, stream>>>(x, st);
    finalize_stats<<<1, 64, 0, stream>>>(st);

    // dest-sorted CSR via two-pass counting sort (coalesced writes, no global float atomics)
    part_kernel<<<NPART, 256, 0, stream>>>(ei, ea, gcur, ent2);
    bucket_csr<<<NBUK, 256, 0, stream>>>(ent2, gcur, ent, rng, dis);

    // GCN layer 1, commuted: a1 = S·normalize(x) (64 cols), then g1 = a1 @ W1 (96 cols)
    gcn_gather<16, true><<<NN * 16 / 256, 256, 0, stream>>>(x, rng, ent, dis, st, a1);
    gemm_tiled<64, 96, 32, 192, false, false, false><<<NN / 32, 192, 0, stream>>>(
        a1, conv1_w, nullptr, nullptr, nullptr, g1, 96);

    // GCN layer 2: h2 = relu(g1+b1) @ W2 (64 cols), then g2 = S·h2
    gemm_tiled<96, 64, 64, 256, true, false, false><<<NN / 64, 256, 0, stream>>>(
        g1, conv2_w, conv1_b, nullptr, nullptr, h2, 64);
    gcn_gather<16, false><<<NN * 16 / 256, 256, 0, stream>>>(h2, rng, ent, dis, nullptr, g2);

    // LSTM input transform: xg = relu(g2+b2) @ w_ih^T + b_ih + b_hh (both col-halves in one launch)
    gemm_tiled<64, 128, 32, 256, true, true, true><<<dim3(NN / 32, 2), 256, 0, stream>>>(
        g2, w_ih, conv2_b, b_ih, b_hh, xg, 256);

    // LSTM recurrence (8 seqs/block, 1024 threads: LDS-resident weights, quarter-row split)
    lstm_kernel<<<SS / 8, 1024, 0, stream>>>(xg, w_hh, hl);

    // FC head + softmax
    head_kernel<<<SS, 128, 0, stream>>>(hl, fc1_w, fc1_b, fc2_w, fc2_b, out);
}

// Round 9
// 551.833 us; speedup vs baseline: 1.1803x; 1.1803x over previous
//
#include <hip/hip_runtime.h>
#include <hip/hip_bf16.h>

#define NN 102400      // B*T*NODES
#define DD 64
#define EE 1638400
#define L1C 96
#define L2C 64
#define TT 32
#define NODESC 400
#define BB 8
#define SS 3200        // B*NODES
#define G4 256         // 4*D

#define NBUK 400       // coarse buckets (node >> 8), NN = 400*256 exactly
#define BCAP 5120      // slots per bucket (mean 4096, sd 64 -> +16 sigma)
#define PCHUNK 8192
#define NPART (EE / PCHUNK)   // 200

// ---------------- workspace layout (floats) ----------------
// [0, 26,214,400): ent | a1 | g1  -> all dead before xg overwrites the region
#define OFF_ENT  ((size_t)0)          // NBUK*BCAP int2 = 4,096,000 floats
#define OFF_A1   ((size_t)4096000)    // NN*64 -> ends 10,649,600
#define OFF_G1   ((size_t)10649600)   // NN*96 -> ends 20,480,000
#define OFF_XG   ((size_t)0)          // NN*256 = 26,214,400
#define OFF_ENT2 ((size_t)26214400)   // staging, 4,096,000 (dead before h2 written)
#define OFF_H2   ((size_t)26214400)   // NN*64 -> ends 32,768,000
#define OFF_G2   ((size_t)32768000)   // NN*64 -> ends 39,321,600
#define OFF_GCUR ((size_t)39321600)   // 400 cursors padded x16 ints = 6400
#define OFF_DIS  ((size_t)39328000)   // NN -> ends 39,430,400
#define OFF_RNG  ((size_t)39430400)   // NN int2 -> ends 39,635,200
#define OFF_HL   ((size_t)39635200)   // SS*64 -> ends 39,840,000
#define OFF_ST   ((size_t)39840000)   // 256 -> total 39,840,256 floats (159.4 MB)

typedef __attribute__((ext_vector_type(8))) short s16x8;   // 8 bf16 in 4 VGPRs
typedef __attribute__((ext_vector_type(4))) float f32x4;

__device__ __forceinline__ void fma4(float4& a, float s, const float4& w) {
    a.x = fmaf(s, w.x, a.x); a.y = fmaf(s, w.y, a.y);
    a.z = fmaf(s, w.z, a.z); a.w = fmaf(s, w.w, a.w);
}
__device__ __forceinline__ float rcp_f(float x) { return __builtin_amdgcn_rcpf(x); }
__device__ __forceinline__ float sigm_f(float x) {
    x = fminf(fmaxf(x, -30.f), 30.f);
    return rcp_f(1.f + __expf(-x));
}
__device__ __forceinline__ float tanh_f(float x) {
    x = fminf(fmaxf(x, -15.f), 15.f);
    float e = __expf(2.f * x);
    return (e - 1.f) * rcp_f(e + 1.f);
}
__device__ __forceinline__ unsigned short f32_bf16_rtne(float f) {
    unsigned int u = __float_as_uint(f);
    unsigned int r = u + 0x7fffu + ((u >> 16) & 1u);
    return (unsigned short)(r >> 16);
}
__device__ __forceinline__ float bf16_f32(unsigned short h) {
    return __uint_as_float(((unsigned int)h) << 16);
}

// ---------------- init: zero bucket cursors + stats ----------------
__global__ void init_zero(int* gcur, float* st) {
    int idx = blockIdx.x * 256 + threadIdx.x;
    if (idx < NBUK * 16) gcur[idx] = 0;
    if (blockIdx.x == 0 && threadIdx.x < 128) st[threadIdx.x] = 0.f;
}

// ---------------- normalization stats ----------------
__global__ __launch_bounds__(256) void col_sums(const float* __restrict__ x, float* __restrict__ st) {
    int c = threadIdx.x & 63;
    size_t i = (size_t)blockIdx.x * 256 + threadIdx.x;
    size_t stride = (size_t)gridDim.x * 256;
    float s = 0.f, q = 0.f;
    for (size_t e = i; e < (size_t)NN * 64; e += stride) {
        float v = x[e]; s += v; q = fmaf(v, v, q);
    }
    __shared__ float ls[128];
    if (threadIdx.x < 128) ls[threadIdx.x] = 0.f;
    __syncthreads();
    atomicAdd(&ls[c], s); atomicAdd(&ls[64 + c], q);
    __syncthreads();
    if (threadIdx.x < 128) atomicAdd(&st[threadIdx.x], ls[threadIdx.x]);
}

__global__ void finalize_stats(float* st) {
    int c = threadIdx.x;
    if (c < 64) {
        float s = st[c], q = st[64 + c];
        float mean = s / (float)NN;
        float var = (q - s * s / (float)NN) / (float)(NN - 1);
        st[128 + c] = mean;
        st[192 + c] = rsqrtf(fmaxf(var, 1e-20f));
    }
}

// ---------------- pass 1: coarse bucket partition (contiguous block-local runs) ----------------
// Entry staging format: meta = src | (dst&255)<<24 (src < 2^17), w = |ea| bits.
__global__ __launch_bounds__(256) void part_kernel(const int* __restrict__ ei, const float* __restrict__ ea,
                                                   int* __restrict__ gcur, int2* __restrict__ ent2) {
    __shared__ int lhist[NBUK];
    __shared__ int lbase[NBUK];
    const int tid = threadIdx.x;
    const int e0 = blockIdx.x * PCHUNK;
    for (int i = tid; i < NBUK; i += 256) lhist[i] = 0;
    __syncthreads();
    #pragma unroll 4
    for (int i = 0; i < PCHUNK / 256; ++i) {
        int d = ei[EE + e0 + i * 256 + tid];
        atomicAdd(&lhist[d >> 8], 1);
    }
    __syncthreads();
    // reserve one contiguous range per bucket (gcur padded: 1 counter / 64B line)
    for (int i = tid; i < NBUK; i += 256) {
        lbase[i] = atomicAdd(&gcur[i * 16], lhist[i]);
        lhist[i] = 0;
    }
    __syncthreads();
    for (int i = 0; i < PCHUNK / 256; ++i) {
        int e = e0 + i * 256 + tid;
        int d = ei[EE + e];
        int s = ei[e];
        float w = fabsf(ea[2 * (size_t)e]);
        int b = d >> 8;
        int local = atomicAdd(&lhist[b], 1);
        int pos = lbase[b] + local;
        if (pos < BCAP)
            ent2[(size_t)b * BCAP + pos] = make_int2(s | ((d & 255) << 24), __float_as_int(w));
    }
}

// ---------------- pass 2: per-bucket counting sort in LDS + rng + dis ----------------
__global__ __launch_bounds__(256) void bucket_csr(const int2* __restrict__ ent2, const int* __restrict__ gcur,
                                                  int2* __restrict__ ent, int2* __restrict__ rng,
                                                  float* __restrict__ dis) {
    __shared__ int nhist[256];
    __shared__ int scn[256];
    __shared__ float wsum[256];
    __shared__ int pcur[256];
    const int tid = threadIdx.x;
    const int b = blockIdx.x;
    const int base = b * BCAP;
    int cnt = gcur[b * 16];
    if (cnt > BCAP) cnt = BCAP;
    nhist[tid] = 0;
    wsum[tid] = 0.f;
    __syncthreads();
    for (int e = tid; e < cnt; e += 256) {
        int2 en = ent2[base + e];
        int dl = ((unsigned)en.x) >> 24;
        atomicAdd(&nhist[dl], 1);
        atomicAdd(&wsum[dl], __int_as_float(en.y));
    }
    __syncthreads();
    int c = nhist[tid];
    scn[tid] = c;
    __syncthreads();
    for (int d = 1; d < 256; d <<= 1) {
        int t = (tid >= d) ? scn[tid - d] : 0;
        __syncthreads();
        scn[tid] += t;
        __syncthreads();
    }
    int ps = scn[tid] - c;                       // exclusive prefix within bucket
    rng[b * 256 + tid] = make_int2(base + ps, base + ps + c);
    dis[b * 256 + tid] = rsqrtf(1.f + wsum[tid]); // self-loop weight 1 folded in
    pcur[tid] = ps;
    __syncthreads();
    for (int e = tid; e < cnt; e += 256) {
        int2 en = ent2[base + e];
        int dl = ((unsigned)en.x) >> 24;
        int local = atomicAdd(&pcur[dl], 1);
        ent[base + local] = make_int2(en.x & 0xFFFFFF, en.y);
    }
}

// ---------------- tiled f32 GEMM ----------------
template<int K, int NC, int MB, int THREADS, bool PRELU, bool TRANSW, bool XGOUT>
__global__ __launch_bounds__(THREADS) void gemm_tiled(
    const float* __restrict__ A, const float* __restrict__ Wm,
    const float* __restrict__ bin, const float* __restrict__ bo1, const float* __restrict__ bo2,
    float* __restrict__ Cm, int ldC)
{
    __shared__ float As[MB * K];
    __shared__ float Ws[K * NC];
    const int cb0 = TRANSW ? ((int)blockIdx.y * NC) : 0;   // xg column-half select

    if (!TRANSW) {
        for (int i = threadIdx.x; i < K * NC / 4; i += THREADS)
            ((float4*)Ws)[i] = ((const float4*)Wm)[i];
    } else {
        for (int i = threadIdx.x; i < NC * (K / 4); i += THREADS) {
            int g = i / (K / 4); int d = (i % (K / 4)) * 4;
            float4 v = *(const float4*)(Wm + (size_t)(cb0 + g) * K + d);
            Ws[(d + 0) * NC + g] = v.x; Ws[(d + 1) * NC + g] = v.y;
            Ws[(d + 2) * NC + g] = v.z; Ws[(d + 3) * NC + g] = v.w;
        }
    }
    size_t row0 = (size_t)blockIdx.x * MB;
    for (int i = threadIdx.x; i < MB * (K / 4); i += THREADS) {
        int r = i / (K / 4); int c = (i % (K / 4)) * 4;
        float4 a = *(const float4*)(A + (row0 + r) * K + c);
        if (PRELU) {
            a.x = fmaxf(a.x + bin[c + 0], 0.f); a.y = fmaxf(a.y + bin[c + 1], 0.f);
            a.z = fmaxf(a.z + bin[c + 2], 0.f); a.w = fmaxf(a.w + bin[c + 3], 0.f);
        }
        ((float4*)As)[i] = a;
    }
    __syncthreads();

    constexpr int NCT = NC / 4;
    int tc = threadIdx.x % NCT;
    int tr = threadIdx.x / NCT;
    int r = tr * 4;
    float4 acc[4];
    acc[0] = acc[1] = acc[2] = acc[3] = make_float4(0.f, 0.f, 0.f, 0.f);

    #pragma unroll 8
    for (int d4 = 0; d4 < K / 4; ++d4) {
        float4 w0 = ((const float4*)Ws)[(4 * d4 + 0) * NCT + tc];
        float4 w1 = ((const float4*)Ws)[(4 * d4 + 1) * NCT + tc];
        float4 w2 = ((const float4*)Ws)[(4 * d4 + 2) * NCT + tc];
        float4 w3 = ((const float4*)Ws)[(4 * d4 + 3) * NCT + tc];
        #pragma unroll
        for (int i = 0; i < 4; ++i) {
            float4 av = ((const float4*)As)[(r + i) * (K / 4) + d4];
            fma4(acc[i], av.x, w0); fma4(acc[i], av.y, w1);
            fma4(acc[i], av.z, w2); fma4(acc[i], av.w, w3);
        }
    }

    if (!XGOUT) {
        #pragma unroll
        for (int i = 0; i < 4; ++i) {
            size_t row = row0 + r + i;
            *(float4*)(Cm + row * ldC + tc * 4) = acc[i];
        }
    } else {
        int cb = cb0 + tc * 4;
        float4 bs;
        bs.x = bo1[cb + 0] + bo2[cb + 0]; bs.y = bo1[cb + 1] + bo2[cb + 1];
        bs.z = bo1[cb + 2] + bo2[cb + 2]; bs.w = bo1[cb + 3] + bo2[cb + 3];
        #pragma unroll
        for (int i = 0; i < 4; ++i) {
            int n = (int)row0 + r + i;                      // n = b*T*NODES + t*NODES + node
            int b_ = n / (TT * NODESC);
            int rem = n - b_ * (TT * NODESC);
            int t = rem / NODESC;
            int node = rem - t * NODESC;
            int orow = (b_ * NODESC + node) * TT + t;       // seq-major, time inner
            float4 o = acc[i];
            o.x += bs.x; o.y += bs.y; o.z += bs.z; o.w += bs.w;
            *(float4*)(Cm + (size_t)orow * ldC + cb) = o;
        }
    }
}

// ---------------- GCN aggregation: gather over packed CSR (rng int2 ranges) ----------------
// g[n] = dis[n] * ( dis[n]*h[n] + sum_e w_e*dis[src_e]*h[src_e] )
template<int C4, bool NORM>
__global__ __launch_bounds__(256) void gcn_gather(const float* __restrict__ h, const int2* __restrict__ rng,
                                                  const int2* __restrict__ ent, const float* __restrict__ dis,
                                                  const float* __restrict__ st, float* __restrict__ g) {
    unsigned int idx = blockIdx.x * 256 + threadIdx.x;
    unsigned int n = idx / C4, q = idx % C4;
    float4 mean4, istd4;
    if (NORM) {
        mean4 = ((const float4*)(st + 128))[q];
        istd4 = ((const float4*)(st + 192))[q];
    }
    float dn = dis[n];
    float4 acc = ((const float4*)h)[(size_t)n * C4 + q];
    if (NORM) {
        acc.x = (acc.x - mean4.x) * istd4.x; acc.y = (acc.y - mean4.y) * istd4.y;
        acc.z = (acc.z - mean4.z) * istd4.z; acc.w = (acc.w - mean4.w) * istd4.w;
    }
    acc.x *= dn; acc.y *= dn; acc.z *= dn; acc.w *= dn;
    int2 r = rng[n];
    for (int e = r.x; e < r.y; ++e) {
        int2 en = ent[e];
        float w = __int_as_float(en.y) * dis[en.x];
        float4 v = ((const float4*)h)[(size_t)en.x * C4 + q];
        if (NORM) {
            v.x = (v.x - mean4.x) * istd4.x; v.y = (v.y - mean4.y) * istd4.y;
            v.z = (v.z - mean4.z) * istd4.z; v.w = (v.w - mean4.w) * istd4.w;
        }
        fma4(acc, w, v);
    }
    acc.x *= dn; acc.y *= dn; acc.z *= dn; acc.w *= dn;
    ((float4*)g)[(size_t)n * C4 + q] = acc;
}

// ---------------- LSTM (recurrent part; xg precomputed) ----------------
// R4-R8 lesson: scalar-FMA formulations are cornered (VGPR demotion / L2 BW /
// LDS issue floor). So: MFMA. Per step, per block of 16 seqs: gates[16 seqs x
// 256 rows] = h[16x64] @ whh^T via mfma_f32_16x16x32_bf16. Precision: hi/lo
// bf16 split of BOTH operands, 3 MFMAs (AhiBhi + AloBhi + AhiBlo, err ~2^-18).
// 1024 threads = 16 waves; wave wv owns gate tile [16 gates]; B-frags = 16
// loop-invariant VGPRs (below the observed 32-reg demotion threshold).
// h stored in LDS as packed (hi | lo<<16) uint, written by activation threads.
// Layouts (verified, m89/m120): A[m=lane&15][k=(lane>>4)*8+j],
// B[n=lane&15][k=(lane>>4)*8+j], C: col=lane&15, row=(lane>>4)*4+reg.
#define HP_LD 66   // hpack row stride (uints): 8B-aligned rows, spreads banks
#define GP_LD 257  // gp row stride (floats)

__global__ __launch_bounds__(1024, 1) void lstm_kernel(const float* __restrict__ xg, const float* __restrict__ whh,
                                                       float* __restrict__ hlast) {
    __shared__ __align__(16) unsigned int hpack[16 * HP_LD];  // h as bf16 hi|lo
    __shared__ float gp[16 * GP_LD];                          // gate pre-activations
    const int tid  = threadIdx.x;       // 0..1023
    const int lane = tid & 63;
    const int wv   = tid >> 6;          // wave 0..15 = gate tile (dot) and seq (act)
    const int n15  = lane & 15;         // A: seq m / B: gate-in-tile n
    const int quad = lane >> 4;         // k sub-block
    const int gate = wv * 16 + n15;
    const int qa   = wv;                // activation seq 0..15
    const int ja   = lane;              // activation hidden unit 0..63

    // ---- loop-invariant B-frags: w_hh row `gate`, bf16 hi/lo split ----
    s16x8 bhi0, bhi1, blo0, blo1;
    {
        const float* wp0 = whh + (size_t)gate * 64 + 0 * 32 + quad * 8;
        const float* wp1 = whh + (size_t)gate * 64 + 1 * 32 + quad * 8;
        #pragma unroll
        for (int j = 0; j < 8; ++j) {
            float w0 = wp0[j], w1 = wp1[j];
            unsigned short h0 = f32_bf16_rtne(w0);
            unsigned short h1 = f32_bf16_rtne(w1);
            bhi0[j] = (short)h0; blo0[j] = (short)f32_bf16_rtne(w0 - bf16_f32(h0));
            bhi1[j] = (short)h1; blo1[j] = (short)f32_bf16_rtne(w1 - bf16_f32(h1));
        }
    }

    // ---- init h = 0, prefetch first xg gate inputs ----
    for (int i = tid; i < 16 * HP_LD; i += 1024) hpack[i] = 0u;
    float c_reg = 0.f, hn = 0.f;
    const float* xa = xg + ((size_t)blockIdx.x * 16 + qa) * TT * G4 + ja;
    float xi = xa[0], xf = xa[64], xgv = xa[128], xo = xa[192];
    __syncthreads();

    for (int t = 0; t < TT; ++t) {
        // prefetch next step's gate inputs
        const int tn = (t + 1 < TT) ? t + 1 : t;
        const float* xan = xa + tn * G4;
        float ni = xan[0], nf = xan[64], ng = xan[128], no = xan[192];

        // ---- dot phase: 6 MFMAs ----
        f32x4 c = {0.f, 0.f, 0.f, 0.f};
        #pragma unroll
        for (int kc = 0; kc < 2; ++kc) {
            const uint2* hp = (const uint2*)(hpack + n15 * HP_LD + kc * 32 + quad * 8);
            uint2 p0 = hp[0], p1 = hp[1], p2 = hp[2], p3 = hp[3];
            s16x8 ahi, alo;
            ahi[0] = (short)(p0.x & 0xffff); alo[0] = (short)(p0.x >> 16);
            ahi[1] = (short)(p0.y & 0xffff); alo[1] = (short)(p0.y >> 16);
            ahi[2] = (short)(p1.x & 0xffff); alo[2] = (short)(p1.x >> 16);
            ahi[3] = (short)(p1.y & 0xffff); alo[3] = (short)(p1.y >> 16);
            ahi[4] = (short)(p2.x & 0xffff); alo[4] = (short)(p2.x >> 16);
            ahi[5] = (short)(p2.y & 0xffff); alo[5] = (short)(p2.y >> 16);
            ahi[6] = (short)(p3.x & 0xffff); alo[6] = (short)(p3.x >> 16);
            ahi[7] = (short)(p3.y & 0xffff); alo[7] = (short)(p3.y >> 16);
            const s16x8 bh = kc ? bhi1 : bhi0;
            const s16x8 bl = kc ? blo1 : blo0;
            c = __builtin_amdgcn_mfma_f32_16x16x32_bf16(ahi, bh, c, 0, 0, 0);
            c = __builtin_amdgcn_mfma_f32_16x16x32_bf16(alo, bh, c, 0, 0, 0);
            c = __builtin_amdgcn_mfma_f32_16x16x32_bf16(ahi, bl, c, 0, 0, 0);
        }
        // C: lane holds seqs m = quad*4+r, gate column `gate`
        #pragma unroll
        for (int r = 0; r < 4; ++r)
            gp[(quad * 4 + r) * GP_LD + gate] = c[r];
        __syncthreads();

        // ---- activation phase: thread (qa, ja) ----
        {
            float gi = gp[qa * GP_LD + ja]        + xi;
            float gf = gp[qa * GP_LD + 64 + ja]   + xf;
            float gg = gp[qa * GP_LD + 128 + ja]  + xgv;
            float go = gp[qa * GP_LD + 192 + ja]  + xo;
            c_reg = sigm_f(gf) * c_reg + sigm_f(gi) * tanh_f(gg);
            hn = sigm_f(go) * tanh_f(c_reg);
            unsigned short hh = f32_bf16_rtne(hn);
            unsigned short hl = f32_bf16_rtne(hn - bf16_f32(hh));
            hpack[qa * HP_LD + ja] = (unsigned int)hh | ((unsigned int)hl << 16);
        }
        __syncthreads();
        xi = ni; xf = nf; xgv = ng; xo = no;
    }
    hlast[((size_t)blockIdx.x * 16 + qa) * 64 + ja] = hn;
}

// ---------------- FC head + softmax ----------------
__global__ __launch_bounds__(128) void head_kernel(const float* __restrict__ hl,
                                                   const float* __restrict__ w1, const float* __restrict__ b1,
                                                   const float* __restrict__ w2, const float* __restrict__ b2,
                                                   float* __restrict__ out) {
    __shared__ float hrow[64];
    __shared__ float a1[128];
    __shared__ float lg[3];
    int s = blockIdx.x, tid = threadIdx.x;
    if (tid < 64) hrow[tid] = hl[(size_t)s * 64 + tid];
    __syncthreads();
    {
        const float4* wr = (const float4*)(w1 + (size_t)tid * 64);
        const float4* hq = (const float4*)hrow;
        float4 acc = make_float4(0.f, 0.f, 0.f, 0.f);
        #pragma unroll
        for (int k = 0; k < 16; ++k) {
            float4 wv = wr[k]; float4 hv = hq[k];
            acc.x = fmaf(wv.x, hv.x, acc.x); acc.y = fmaf(wv.y, hv.y, acc.y);
            acc.z = fmaf(wv.z, hv.z, acc.z); acc.w = fmaf(wv.w, hv.w, acc.w);
        }
        a1[tid] = fmaxf((acc.x + acc.y) + (acc.z + acc.w) + b1[tid], 0.f);
    }
    __syncthreads();
    if (tid < 3) {
        const float4* wr = (const float4*)(w2 + (size_t)tid * 128);
        const float4* aq = (const float4*)a1;
        float4 acc = make_float4(0.f, 0.f, 0.f, 0.f);
        #pragma unroll
        for (int k = 0; k < 32; ++k) {
            float4 wv = wr[k]; float4 av = aq[k];
            acc.x = fmaf(wv.x, av.x, acc.x); acc.y = fmaf(wv.y, av.y, acc.y);
            acc.z = fmaf(wv.z, av.z, acc.z); acc.w = fmaf(wv.w, av.w, acc.w);
        }
        lg[tid] = (acc.x + acc.y) + (acc.z + acc.w) + b2[tid];
    }
    __syncthreads();
    if (tid == 0) {
        float m = fmaxf(lg[0], fmaxf(lg[1], lg[2]));
        float e0 = __expf(lg[0] - m), e1 = __expf(lg[1] - m), e2 = __expf(lg[2] - m);
        float inv = 1.f / (e0 + e1 + e2);
        out[(size_t)s * 3 + 0] = e0 * inv;
        out[(size_t)s * 3 + 1] = e1 * inv;
        out[(size_t)s * 3 + 2] = e2 * inv;
    }
}

extern "C" void kernel_launch(void* const* d_in, const int* in_sizes, int n_in,
                              void* d_out, int out_size, void* d_ws, size_t ws_size,
                              hipStream_t stream) {
    (void)in_sizes; (void)n_in; (void)out_size; (void)ws_size;
    const float* x        = (const float*)d_in[0];
    const float* ea       = (const float*)d_in[1];
    const float* conv1_w  = (const float*)d_in[2];
    const float* conv1_b  = (const float*)d_in[3];
    const float* conv2_w  = (const float*)d_in[4];
    const float* conv2_b  = (const float*)d_in[5];
    const float* w_ih     = (const float*)d_in[6];
    const float* w_hh     = (const float*)d_in[7];
    const float* b_ih     = (const float*)d_in[8];
    const float* b_hh     = (const float*)d_in[9];
    const float* fc1_w    = (const float*)d_in[10];
    const float* fc1_b    = (const float*)d_in[11];
    const float* fc2_w    = (const float*)d_in[12];
    const float* fc2_b    = (const float*)d_in[13];
    const int*   ei       = (const int*)d_in[14];
    float* out = (float*)d_out;

    float* W    = (float*)d_ws;
    int2*  ent  = (int2*)(W + OFF_ENT);
    float* a1   = W + OFF_A1;
    float* g1   = W + OFF_G1;
    float* xg   = W + OFF_XG;
    int2*  ent2 = (int2*)(W + OFF_ENT2);
    float* h2   = W + OFF_H2;
    float* g2   = W + OFF_G2;
    int*   gcur = (int*)(W + OFF_GCUR);
    float* dis  = W + OFF_DIS;
    int2*  rng  = (int2*)(W + OFF_RNG);
    float* hl   = W + OFF_HL;
    float* st   = W + OFF_ST;

    // init + normalization stats (normalization itself fused into gather-1)
    init_zero<<<26, 256, 0, stream>>>(gcur, st);
    col_sums<<<1024, 256, 0, stream>>>(x, st);
    finalize_stats<<<1, 64, 0, stream>>>(st);

    // dest-sorted CSR via two-pass counting sort (coalesced writes, no global float atomics)
    part_kernel<<<NPART, 256, 0, stream>>>(ei, ea, gcur, ent2);
    bucket_csr<<<NBUK, 256, 0, stream>>>(ent2, gcur, ent, rng, dis);

    // GCN layer 1, commuted: a1 = S·normalize(x) (64 cols), then g1 = a1 @ W1 (96 cols)
    gcn_gather<16, true><<<NN * 16 / 256, 256, 0, stream>>>(x, rng, ent, dis, st, a1);
    gemm_tiled<64, 96, 32, 192, false, false, false><<<NN / 32, 192, 0, stream>>>(
        a1, conv1_w, nullptr, nullptr, nullptr, g1, 96);

    // GCN layer 2: h2 = relu(g1+b1) @ W2 (64 cols), then g2 = S·h2
    gemm_tiled<96, 64, 64, 256, true, false, false><<<NN / 64, 256, 0, stream>>>(
        g1, conv2_w, conv1_b, nullptr, nullptr, h2, 64);
    gcn_gather<16, false><<<NN * 16 / 256, 256, 0, stream>>>(h2, rng, ent, dis, nullptr, g2);

    // LSTM input transform: xg = relu(g2+b2) @ w_ih^T + b_ih + b_hh (both col-halves in one launch)
    gemm_tiled<64, 128, 32, 256, true, true, true><<<dim3(NN / 32, 2), 256, 0, stream>>>(
        g2, w_ih, conv2_b, b_ih, b_hh, xg, 256);

    // LSTM recurrence: MFMA path, 16 seqs/block, 1024 threads
    lstm_kernel<<<SS / 16, 1024, 0, stream>>>(xg, w_hh, hl);

    // FC head + softmax
    head_kernel<<<SS, 128, 0, stream>>>(hl, fc1_w, fc1_b, fc2_w, fc2_b, out);
}

// Round 10
// 522.578 us; speedup vs baseline: 1.2463x; 1.0560x over previous
//
#include <hip/hip_runtime.h>
#include <hip/hip_bf16.h>

#define NN 102400      // B*T*NODES
#define DD 64
#define EE 1638400
#define L1C 96
#define L2C 64
#define TT 32
#define NODESC 400
#define BB 8
#define SS 3200        // B*NODES
#define G4 256         // 4*D

#define NBUK 400       // coarse buckets (node >> 8), NN = 400*256 exactly
#define BCAP 5120      // slots per bucket (mean 4096, sd 64 -> +16 sigma)
#define PCHUNK 8192
#define NPART (EE / PCHUNK)   // 200

// ---------------- workspace layout (floats) ----------------
// [0, 26,214,400): ent | a1 | g1  -> all dead before xg overwrites the region
#define OFF_ENT  ((size_t)0)          // NBUK*BCAP int2 = 4,096,000 floats
#define OFF_A1   ((size_t)4096000)    // NN*64 -> ends 10,649,600
#define OFF_G1   ((size_t)10649600)   // NN*96 -> ends 20,480,000
#define OFF_XG   ((size_t)0)          // NN*256 = 26,214,400
#define OFF_ENT2 ((size_t)26214400)   // staging, 4,096,000 (dead before h2 written)
#define OFF_H2   ((size_t)26214400)   // NN*64 -> ends 32,768,000
#define OFF_G2   ((size_t)32768000)   // NN*64 -> ends 39,321,600
#define OFF_GCUR ((size_t)39321600)   // 400 cursors padded x16 ints = 6400
#define OFF_DIS  ((size_t)39328000)   // NN -> ends 39,430,400
#define OFF_RNG  ((size_t)39430400)   // NN int2 -> ends 39,635,200
#define OFF_HL   ((size_t)39635200)   // SS*64 -> ends 39,840,000
#define OFF_ST   ((size_t)39840000)   // 256 -> ends 39,840,256
#define OFF_WT   ((size_t)39840256)   // w_ih^T [2][64][128] = 16384 -> total 39,856,640 (159.4 MB)

typedef __attribute__((ext_vector_type(8))) short s16x8;   // 8 bf16 in 4 VGPRs
typedef __attribute__((ext_vector_type(4))) float f32x4;

__device__ __forceinline__ void fma4(float4& a, float s, const float4& w) {
    a.x = fmaf(s, w.x, a.x); a.y = fmaf(s, w.y, a.y);
    a.z = fmaf(s, w.z, a.z); a.w = fmaf(s, w.w, a.w);
}
__device__ __forceinline__ float rcp_f(float x) { return __builtin_amdgcn_rcpf(x); }
__device__ __forceinline__ float sigm_f(float x) {
    x = fminf(fmaxf(x, -30.f), 30.f);
    return rcp_f(1.f + __expf(-x));
}
__device__ __forceinline__ float tanh_f(float x) {
    x = fminf(fmaxf(x, -15.f), 15.f);
    float e = __expf(2.f * x);
    return (e - 1.f) * rcp_f(e + 1.f);
}
__device__ __forceinline__ unsigned short f32_bf16_rtne(float f) {
    unsigned int u = __float_as_uint(f);
    unsigned int r = u + 0x7fffu + ((u >> 16) & 1u);
    return (unsigned short)(r >> 16);
}
__device__ __forceinline__ float bf16_f32(unsigned short h) {
    return __uint_as_float(((unsigned int)h) << 16);
}

// ---------------- init: zero bucket cursors + stats ----------------
__global__ void init_zero(int* gcur, float* st) {
    int idx = blockIdx.x * 256 + threadIdx.x;
    if (idx < NBUK * 16) gcur[idx] = 0;
    if (blockIdx.x == 0 && threadIdx.x < 128) st[threadIdx.x] = 0.f;
}

// ---------------- w_ih pre-transpose: wT[h][d][g] = w_ih[h*128+g][d] ----------------
// Kills the 16-way LDS bank conflicts the in-GEMM transpose staging caused
// (R9 post-mortem: SQ_LDS_BANK_CONFLICT 2.46e7 == 45% of xg-GEMM cycles).
__global__ void transpose_wih(const float* __restrict__ w_ih, float* __restrict__ wT) {
    int i = blockIdx.x * 256 + threadIdx.x;   // 0..16383
    int g = i >> 6, d = i & 63;
    float v = w_ih[i];
    int h = g >> 7, gl = g & 127;
    wT[h * 8192 + d * 128 + gl] = v;
}

// ---------------- normalization stats ----------------
__global__ __launch_bounds__(256) void col_sums(const float* __restrict__ x, float* __restrict__ st) {
    int c = threadIdx.x & 63;
    size_t i = (size_t)blockIdx.x * 256 + threadIdx.x;
    size_t stride = (size_t)gridDim.x * 256;
    float s = 0.f, q = 0.f;
    for (size_t e = i; e < (size_t)NN * 64; e += stride) {
        float v = x[e]; s += v; q = fmaf(v, v, q);
    }
    __shared__ float ls[128];
    if (threadIdx.x < 128) ls[threadIdx.x] = 0.f;
    __syncthreads();
    atomicAdd(&ls[c], s); atomicAdd(&ls[64 + c], q);
    __syncthreads();
    if (threadIdx.x < 128) atomicAdd(&st[threadIdx.x], ls[threadIdx.x]);
}

__global__ void finalize_stats(float* st) {
    int c = threadIdx.x;
    if (c < 64) {
        float s = st[c], q = st[64 + c];
        float mean = s / (float)NN;
        float var = (q - s * s / (float)NN) / (float)(NN - 1);
        st[128 + c] = mean;
        st[192 + c] = rsqrtf(fmaxf(var, 1e-20f));
    }
}

// ---------------- pass 1: coarse bucket partition (contiguous block-local runs) ----------------
// Entry staging format: meta = src | (dst&255)<<24 (src < 2^17), w = |ea| bits.
__global__ __launch_bounds__(256) void part_kernel(const int* __restrict__ ei, const float* __restrict__ ea,
                                                   int* __restrict__ gcur, int2* __restrict__ ent2) {
    __shared__ int lhist[NBUK];
    __shared__ int lbase[NBUK];
    const int tid = threadIdx.x;
    const int e0 = blockIdx.x * PCHUNK;
    for (int i = tid; i < NBUK; i += 256) lhist[i] = 0;
    __syncthreads();
    #pragma unroll 4
    for (int i = 0; i < PCHUNK / 256; ++i) {
        int d = ei[EE + e0 + i * 256 + tid];
        atomicAdd(&lhist[d >> 8], 1);
    }
    __syncthreads();
    // reserve one contiguous range per bucket (gcur padded: 1 counter / 64B line)
    for (int i = tid; i < NBUK; i += 256) {
        lbase[i] = atomicAdd(&gcur[i * 16], lhist[i]);
        lhist[i] = 0;
    }
    __syncthreads();
    for (int i = 0; i < PCHUNK / 256; ++i) {
        int e = e0 + i * 256 + tid;
        int d = ei[EE + e];
        int s = ei[e];
        float w = fabsf(ea[2 * (size_t)e]);
        int b = d >> 8;
        int local = atomicAdd(&lhist[b], 1);
        int pos = lbase[b] + local;
        if (pos < BCAP)
            ent2[(size_t)b * BCAP + pos] = make_int2(s | ((d & 255) << 24), __float_as_int(w));
    }
}

// ---------------- pass 2: per-bucket counting sort in LDS + rng + dis ----------------
__global__ __launch_bounds__(256) void bucket_csr(const int2* __restrict__ ent2, const int* __restrict__ gcur,
                                                  int2* __restrict__ ent, int2* __restrict__ rng,
                                                  float* __restrict__ dis) {
    __shared__ int nhist[256];
    __shared__ int scn[256];
    __shared__ float wsum[256];
    __shared__ int pcur[256];
    const int tid = threadIdx.x;
    const int b = blockIdx.x;
    const int base = b * BCAP;
    int cnt = gcur[b * 16];
    if (cnt > BCAP) cnt = BCAP;
    nhist[tid] = 0;
    wsum[tid] = 0.f;
    __syncthreads();
    for (int e = tid; e < cnt; e += 256) {
        int2 en = ent2[base + e];
        int dl = ((unsigned)en.x) >> 24;
        atomicAdd(&nhist[dl], 1);
        atomicAdd(&wsum[dl], __int_as_float(en.y));
    }
    __syncthreads();
    int c = nhist[tid];
    scn[tid] = c;
    __syncthreads();
    for (int d = 1; d < 256; d <<= 1) {
        int t = (tid >= d) ? scn[tid - d] : 0;
        __syncthreads();
        scn[tid] += t;
        __syncthreads();
    }
    int ps = scn[tid] - c;                       // exclusive prefix within bucket
    rng[b * 256 + tid] = make_int2(base + ps, base + ps + c);
    dis[b * 256 + tid] = rsqrtf(1.f + wsum[tid]); // self-loop weight 1 folded in
    pcur[tid] = ps;
    __syncthreads();
    for (int e = tid; e < cnt; e += 256) {
        int2 en = ent2[base + e];
        int dl = ((unsigned)en.x) >> 24;
        int local = atomicAdd(&pcur[dl], 1);
        ent[base + local] = make_int2(en.x & 0xFFFFFF, en.y);
    }
}

// ---------------- tiled f32 GEMM ----------------
// Weights always consumed in [K][NC] layout (xg GEMM gets pre-transposed wT;
// XGOUT selects column-half h=blockIdx.y via flat offset cb0*K = h*8192).
template<int K, int NC, int MB, int THREADS, bool PRELU, bool XGOUT>
__global__ __launch_bounds__(THREADS) void gemm_tiled(
    const float* __restrict__ A, const float* __restrict__ Wm,
    const float* __restrict__ bin, const float* __restrict__ bo1, const float* __restrict__ bo2,
    float* __restrict__ Cm, int ldC)
{
    __shared__ float As[MB * K];
    __shared__ float Ws[K * NC];
    const int cb0 = XGOUT ? ((int)blockIdx.y * NC) : 0;
    const float* Wsrc = Wm + (XGOUT ? (size_t)cb0 * K : 0);

    for (int i = threadIdx.x; i < K * NC / 4; i += THREADS)
        ((float4*)Ws)[i] = ((const float4*)Wsrc)[i];

    size_t row0 = (size_t)blockIdx.x * MB;
    for (int i = threadIdx.x; i < MB * (K / 4); i += THREADS) {
        int r = i / (K / 4); int c = (i % (K / 4)) * 4;
        float4 a = *(const float4*)(A + (row0 + r) * K + c);
        if (PRELU) {
            a.x = fmaxf(a.x + bin[c + 0], 0.f); a.y = fmaxf(a.y + bin[c + 1], 0.f);
            a.z = fmaxf(a.z + bin[c + 2], 0.f); a.w = fmaxf(a.w + bin[c + 3], 0.f);
        }
        ((float4*)As)[i] = a;
    }
    __syncthreads();

    constexpr int NCT = NC / 4;
    int tc = threadIdx.x % NCT;
    int tr = threadIdx.x / NCT;
    int r = tr * 4;
    float4 acc[4];
    acc[0] = acc[1] = acc[2] = acc[3] = make_float4(0.f, 0.f, 0.f, 0.f);

    #pragma unroll 8
    for (int d4 = 0; d4 < K / 4; ++d4) {
        float4 w0 = ((const float4*)Ws)[(4 * d4 + 0) * NCT + tc];
        float4 w1 = ((const float4*)Ws)[(4 * d4 + 1) * NCT + tc];
        float4 w2 = ((const float4*)Ws)[(4 * d4 + 2) * NCT + tc];
        float4 w3 = ((const float4*)Ws)[(4 * d4 + 3) * NCT + tc];
        #pragma unroll
        for (int i = 0; i < 4; ++i) {
            float4 av = ((const float4*)As)[(r + i) * (K / 4) + d4];
            fma4(acc[i], av.x, w0); fma4(acc[i], av.y, w1);
            fma4(acc[i], av.z, w2); fma4(acc[i], av.w, w3);
        }
    }

    if (!XGOUT) {
        #pragma unroll
        for (int i = 0; i < 4; ++i) {
            size_t row = row0 + r + i;
            *(float4*)(Cm + row * ldC + tc * 4) = acc[i];
        }
    } else {
        int cb = cb0 + tc * 4;
        float4 bs;
        bs.x = bo1[cb + 0] + bo2[cb + 0]; bs.y = bo1[cb + 1] + bo2[cb + 1];
        bs.z = bo1[cb + 2] + bo2[cb + 2]; bs.w = bo1[cb + 3] + bo2[cb + 3];
        #pragma unroll
        for (int i = 0; i < 4; ++i) {
            int n = (int)row0 + r + i;                      // n = b*T*NODES + t*NODES + node
            int b_ = n / (TT * NODESC);
            int rem = n - b_ * (TT * NODESC);
            int t = rem / NODESC;
            int node = rem - t * NODESC;
            int orow = (b_ * NODESC + node) * TT + t;       // seq-major, time inner
            float4 o = acc[i];
            o.x += bs.x; o.y += bs.y; o.z += bs.z; o.w += bs.w;
            *(float4*)(Cm + (size_t)orow * ldC + cb) = o;
        }
    }
}

// ---------------- GCN aggregation: gather over packed CSR (rng int2 ranges) ----------------
// g[n] = dis[n] * ( dis[n]*h[n] + sum_e w_e*dis[src_e]*h[src_e] )
template<int C4, bool NORM>
__global__ __launch_bounds__(256) void gcn_gather(const float* __restrict__ h, const int2* __restrict__ rng,
                                                  const int2* __restrict__ ent, const float* __restrict__ dis,
                                                  const float* __restrict__ st, float* __restrict__ g) {
    unsigned int idx = blockIdx.x * 256 + threadIdx.x;
    unsigned int n = idx / C4, q = idx % C4;
    float4 mean4, istd4;
    if (NORM) {
        mean4 = ((const float4*)(st + 128))[q];
        istd4 = ((const float4*)(st + 192))[q];
    }
    float dn = dis[n];
    float4 acc = ((const float4*)h)[(size_t)n * C4 + q];
    if (NORM) {
        acc.x = (acc.x - mean4.x) * istd4.x; acc.y = (acc.y - mean4.y) * istd4.y;
        acc.z = (acc.z - mean4.z) * istd4.z; acc.w = (acc.w - mean4.w) * istd4.w;
    }
    acc.x *= dn; acc.y *= dn; acc.z *= dn; acc.w *= dn;
    int2 r = rng[n];
    for (int e = r.x; e < r.y; ++e) {
        int2 en = ent[e];
        float w = __int_as_float(en.y) * dis[en.x];
        float4 v = ((const float4*)h)[(size_t)en.x * C4 + q];
        if (NORM) {
            v.x = (v.x - mean4.x) * istd4.x; v.y = (v.y - mean4.y) * istd4.y;
            v.z = (v.z - mean4.z) * istd4.z; v.w = (v.w - mean4.w) * istd4.w;
        }
        fma4(acc, w, v);
    }
    acc.x *= dn; acc.y *= dn; acc.z *= dn; acc.w *= dn;
    ((float4*)g)[(size_t)n * C4 + q] = acc;
}

// ---------------- LSTM (recurrent part; xg precomputed) ----------------
// MFMA path (R8): per step, gates[16 seqs x 256 rows] = h[16x64] @ whh^T via
// mfma_f32_16x16x32_bf16 with hi/lo bf16 split (3 MFMAs, err ~2^-18).
// 1024 threads = 16 waves; wave wv owns gate tile [16 gates]; B-frags = 16
// loop-invariant VGPRs. h in LDS as packed (hi | lo<<16) uint.
#define HP_LD 66   // hpack row stride (uints)
#define GP_LD 257  // gp row stride (floats)

__global__ __launch_bounds__(1024, 1) void lstm_kernel(const float* __restrict__ xg, const float* __restrict__ whh,
                                                       float* __restrict__ hlast) {
    __shared__ __align__(16) unsigned int hpack[16 * HP_LD];  // h as bf16 hi|lo
    __shared__ float gp[16 * GP_LD];                          // gate pre-activations
    const int tid  = threadIdx.x;       // 0..1023
    const int lane = tid & 63;
    const int wv   = tid >> 6;          // wave 0..15 = gate tile (dot) and seq (act)
    const int n15  = lane & 15;         // A: seq m / B: gate-in-tile n
    const int quad = lane >> 4;         // k sub-block
    const int gate = wv * 16 + n15;
    const int qa   = wv;                // activation seq 0..15
    const int ja   = lane;              // activation hidden unit 0..63

    // ---- loop-invariant B-frags: w_hh row `gate`, bf16 hi/lo split ----
    s16x8 bhi0, bhi1, blo0, blo1;
    {
        const float* wp0 = whh + (size_t)gate * 64 + 0 * 32 + quad * 8;
        const float* wp1 = whh + (size_t)gate * 64 + 1 * 32 + quad * 8;
        #pragma unroll
        for (int j = 0; j < 8; ++j) {
            float w0 = wp0[j], w1 = wp1[j];
            unsigned short h0 = f32_bf16_rtne(w0);
            unsigned short h1 = f32_bf16_rtne(w1);
            bhi0[j] = (short)h0; blo0[j] = (short)f32_bf16_rtne(w0 - bf16_f32(h0));
            bhi1[j] = (short)h1; blo1[j] = (short)f32_bf16_rtne(w1 - bf16_f32(h1));
        }
    }

    // ---- init h = 0, prefetch first xg gate inputs ----
    for (int i = tid; i < 16 * HP_LD; i += 1024) hpack[i] = 0u;
    float c_reg = 0.f, hn = 0.f;
    const float* xa = xg + ((size_t)blockIdx.x * 16 + qa) * TT * G4 + ja;
    float xi = xa[0], xf = xa[64], xgv = xa[128], xo = xa[192];
    __syncthreads();

    for (int t = 0; t < TT; ++t) {
        // prefetch next step's gate inputs
        const int tn = (t + 1 < TT) ? t + 1 : t;
        const float* xan = xa + tn * G4;
        float ni = xan[0], nf = xan[64], ng = xan[128], no = xan[192];

        // ---- dot phase: 6 MFMAs ----
        f32x4 c = {0.f, 0.f, 0.f, 0.f};
        #pragma unroll
        for (int kc = 0; kc < 2; ++kc) {
            const uint2* hp = (const uint2*)(hpack + n15 * HP_LD + kc * 32 + quad * 8);
            uint2 p0 = hp[0], p1 = hp[1], p2 = hp[2], p3 = hp[3];
            s16x8 ahi, alo;
            ahi[0] = (short)(p0.x & 0xffff); alo[0] = (short)(p0.x >> 16);
            ahi[1] = (short)(p0.y & 0xffff); alo[1] = (short)(p0.y >> 16);
            ahi[2] = (short)(p1.x & 0xffff); alo[2] = (short)(p1.x >> 16);
            ahi[3] = (short)(p1.y & 0xffff); alo[3] = (short)(p1.y >> 16);
            ahi[4] = (short)(p2.x & 0xffff); alo[4] = (short)(p2.x >> 16);
            ahi[5] = (short)(p2.y & 0xffff); alo[5] = (short)(p2.y >> 16);
            ahi[6] = (short)(p3.x & 0xffff); alo[6] = (short)(p3.x >> 16);
            ahi[7] = (short)(p3.y & 0xffff); alo[7] = (short)(p3.y >> 16);
            const s16x8 bh = kc ? bhi1 : bhi0;
            const s16x8 bl = kc ? blo1 : blo0;
            c = __builtin_amdgcn_mfma_f32_16x16x32_bf16(ahi, bh, c, 0, 0, 0);
            c = __builtin_amdgcn_mfma_f32_16x16x32_bf16(alo, bh, c, 0, 0, 0);
            c = __builtin_amdgcn_mfma_f32_16x16x32_bf16(ahi, bl, c, 0, 0, 0);
        }
        // C: lane holds seqs m = quad*4+r, gate column `gate`
        #pragma unroll
        for (int r = 0; r < 4; ++r)
            gp[(quad * 4 + r) * GP_LD + gate] = c[r];
        __syncthreads();

        // ---- activation phase: thread (qa, ja) ----
        {
            float gi = gp[qa * GP_LD + ja]        + xi;
            float gf = gp[qa * GP_LD + 64 + ja]   + xf;
            float gg = gp[qa * GP_LD + 128 + ja]  + xgv;
            float go = gp[qa * GP_LD + 192 + ja]  + xo;
            c_reg = sigm_f(gf) * c_reg + sigm_f(gi) * tanh_f(gg);
            hn = sigm_f(go) * tanh_f(c_reg);
            unsigned short hh = f32_bf16_rtne(hn);
            unsigned short hl = f32_bf16_rtne(hn - bf16_f32(hh));
            hpack[qa * HP_LD + ja] = (unsigned int)hh | ((unsigned int)hl << 16);
        }
        __syncthreads();
        xi = ni; xf = nf; xgv = ng; xo = no;
    }
    hlast[((size_t)blockIdx.x * 16 + qa) * 64 + ja] = hn;
}

// ---------------- FC head + softmax ----------------
__global__ __launch_bounds__(128) void head_kernel(const float* __restrict__ hl,
                                                   const float* __restrict__ w1, const float* __restrict__ b1,
                                                   const float* __restrict__ w2, const float* __restrict__ b2,
                                                   float* __restrict__ out) {
    __shared__ float hrow[64];
    __shared__ float a1[128];
    __shared__ float lg[3];
    int s = blockIdx.x, tid = threadIdx.x;
    if (tid < 64) hrow[tid] = hl[(size_t)s * 64 + tid];
    __syncthreads();
    {
        const float4* wr = (const float4*)(w1 + (size_t)tid * 64);
        const float4* hq = (const float4*)hrow;
        float4 acc = make_float4(0.f, 0.f, 0.f, 0.f);
        #pragma unroll
        for (int k = 0; k < 16; ++k) {
            float4 wv = wr[k]; float4 hv = hq[k];
            acc.x = fmaf(wv.x, hv.x, acc.x); acc.y = fmaf(wv.y, hv.y, acc.y);
            acc.z = fmaf(wv.z, hv.z, acc.z); acc.w = fmaf(wv.w, hv.w, acc.w);
        }
        a1[tid] = fmaxf((acc.x + acc.y) + (acc.z + acc.w) + b1[tid], 0.f);
    }
    __syncthreads();
    if (tid < 3) {
        const float4* wr = (const float4*)(w2 + (size_t)tid * 128);
        const float4* aq = (const float4*)a1;
        float4 acc = make_float4(0.f, 0.f, 0.f, 0.f);
        #pragma unroll
        for (int k = 0; k < 32; ++k) {
            float4 wv = wr[k]; float4 av = aq[k];
            acc.x = fmaf(wv.x, av.x, acc.x); acc.y = fmaf(wv.y, av.y, acc.y);
            acc.z = fmaf(wv.z, av.z, acc.z); acc.w = fmaf(wv.w, av.w, acc.w);
        }
        lg[tid] = (acc.x + acc.y) + (acc.z + acc.w) + b2[tid];
    }
    __syncthreads();
    if (tid == 0) {
        float m = fmaxf(lg[0], fmaxf(lg[1], lg[2]));
        float e0 = __expf(lg[0] - m), e1 = __expf(lg[1] - m), e2 = __expf(lg[2] - m);
        float inv = 1.f / (e0 + e1 + e2);
        out[(size_t)s * 3 + 0] = e0 * inv;
        out[(size_t)s * 3 + 1] = e1 * inv;
        out[(size_t)s * 3 + 2] = e2 * inv;
    }
}

extern "C" void kernel_launch(void* const* d_in, const int* in_sizes, int n_in,
                              void* d_out, int out_size, void* d_ws, size_t ws_size,
                              hipStream_t stream) {
    (void)in_sizes; (void)n_in; (void)out_size; (void)ws_size;
    const float* x        = (const float*)d_in[0];
    const float* ea       = (const float*)d_in[1];
    const float* conv1_w  = (const float*)d_in[2];
    const float* conv1_b  = (const float*)d_in[3];
    const float* conv2_w  = (const float*)d_in[4];
    const float* conv2_b  = (const float*)d_in[5];
    const float* w_ih     = (const float*)d_in[6];
    const float* w_hh     = (const float*)d_in[7];
    const float* b_ih     = (const float*)d_in[8];
    const float* b_hh     = (const float*)d_in[9];
    const float* fc1_w    = (const float*)d_in[10];
    const float* fc1_b    = (const float*)d_in[11];
    const float* fc2_w    = (const float*)d_in[12];
    const float* fc2_b    = (const float*)d_in[13];
    const int*   ei       = (const int*)d_in[14];
    float* out = (float*)d_out;

    float* W    = (float*)d_ws;
    int2*  ent  = (int2*)(W + OFF_ENT);
    float* a1   = W + OFF_A1;
    float* g1   = W + OFF_G1;
    float* xg   = W + OFF_XG;
    int2*  ent2 = (int2*)(W + OFF_ENT2);
    float* h2   = W + OFF_H2;
    float* g2   = W + OFF_G2;
    int*   gcur = (int*)(W + OFF_GCUR);
    float* dis  = W + OFF_DIS;
    int2*  rng  = (int2*)(W + OFF_RNG);
    float* hl   = W + OFF_HL;
    float* st   = W + OFF_ST;
    float* wT   = W + OFF_WT;

    // init + normalization stats (normalization itself fused into gather-1)
    init_zero<<<26, 256, 0, stream>>>(gcur, st);
    transpose_wih<<<64, 256, 0, stream>>>(w_ih, wT);
    col_sums<<<1024, 256, 0, stream>>>(x, st);
    finalize_stats<<<1, 64, 0, stream>>>(st);

    // dest-sorted CSR via two-pass counting sort (coalesced writes, no global float atomics)
    part_kernel<<<NPART, 256, 0, stream>>>(ei, ea, gcur, ent2);
    bucket_csr<<<NBUK, 256, 0, stream>>>(ent2, gcur, ent, rng, dis);

    // GCN layer 1, commuted: a1 = S·normalize(x) (64 cols), then g1 = a1 @ W1 (96 cols)
    gcn_gather<16, true><<<NN * 16 / 256, 256, 0, stream>>>(x, rng, ent, dis, st, a1);
    gemm_tiled<64, 96, 32, 192, false, false><<<NN / 32, 192, 0, stream>>>(
        a1, conv1_w, nullptr, nullptr, nullptr, g1, 96);

    // GCN layer 2: h2 = relu(g1+b1) @ W2 (64 cols), then g2 = S·h2
    gemm_tiled<96, 64, 64, 256, true, false><<<NN / 64, 256, 0, stream>>>(
        g1, conv2_w, conv1_b, nullptr, nullptr, h2, 64);
    gcn_gather<16, false><<<NN * 16 / 256, 256, 0, stream>>>(h2, rng, ent, dis, nullptr, g2);

    // LSTM input transform: xg = relu(g2+b2) @ w_ih^T + b_ih + b_hh
    // (pre-transposed wT, conflict-free linear staging; both col-halves via blockIdx.y)
    gemm_tiled<64, 128, 32, 256, true, true><<<dim3(NN / 32, 2), 256, 0, stream>>>(
        g2, wT, conv2_b, b_ih, b_hh, xg, 256);

    // LSTM recurrence: MFMA path, 16 seqs/block, 1024 threads
    lstm_kernel<<<SS / 16, 1024, 0, stream>>>(xg, w_hh, hl);

    // FC head + softmax
    head_kernel<<<SS, 128, 0, stream>>>(hl, fc1_w, fc1_b, fc2_w, fc2_b, out);
}

// Round 11
// 500.746 us; speedup vs baseline: 1.3007x; 1.0436x over previous
//
#include <hip/hip_runtime.h>
#include <hip/hip_bf16.h>

#define NN 102400      // B*T*NODES
#define DD 64
#define EE 1638400
#define L1C 96
#define L2C 64
#define TT 32
#define NODESC 400
#define BB 8
#define SS 3200        // B*NODES
#define G4 256         // 4*D

#define NBUK 400       // coarse buckets (node >> 8), NN = 400*256 exactly
#define BCAP 5120      // slots per bucket (mean 4096, sd 64 -> +16 sigma)
#define PCHUNK 8192
#define NPART (EE / PCHUNK)   // 200

// ---------------- workspace layout (floats) ----------------
// [0, 26,214,400): ent | a1 | g1  -> all dead before xg overwrites the region
#define OFF_ENT  ((size_t)0)          // NBUK*BCAP int2 = 4,096,000 floats
#define OFF_A1   ((size_t)4096000)    // NN*64 -> ends 10,649,600
#define OFF_G1   ((size_t)10649600)   // NN*96 -> ends 20,480,000
#define OFF_XG   ((size_t)0)          // NN*256 = 26,214,400
#define OFF_ENT2 ((size_t)26214400)   // csr staging (4,096,000); then xnd (6,553,600); then h2d
#define OFF_H2   ((size_t)26214400)   // NN*64 -> ends 32,768,000
#define OFF_G2   ((size_t)32768000)   // NN*64 -> ends 39,321,600
#define OFF_GCUR ((size_t)39321600)   // 400 cursors padded x16 ints = 6400
#define OFF_DIS  ((size_t)39328000)   // NN -> ends 39,430,400
#define OFF_RNG  ((size_t)39430400)   // NN int2 -> ends 39,635,200
#define OFF_HL   ((size_t)39635200)   // SS*64 -> ends 39,840,000
#define OFF_ST   ((size_t)39840000)   // 256 -> ends 39,840,256
#define OFF_WT   ((size_t)39840256)   // w_ih^T [2][64][128] = 16384 -> total 39,856,640 (159.4 MB)

typedef __attribute__((ext_vector_type(8))) short s16x8;   // 8 bf16 in 4 VGPRs
typedef __attribute__((ext_vector_type(4))) float f32x4;

__device__ __forceinline__ void fma4(float4& a, float s, const float4& w) {
    a.x = fmaf(s, w.x, a.x); a.y = fmaf(s, w.y, a.y);
    a.z = fmaf(s, w.z, a.z); a.w = fmaf(s, w.w, a.w);
}
__device__ __forceinline__ float rcp_f(float x) { return __builtin_amdgcn_rcpf(x); }
__device__ __forceinline__ float sigm_f(float x) {
    x = fminf(fmaxf(x, -30.f), 30.f);
    return rcp_f(1.f + __expf(-x));
}
__device__ __forceinline__ float tanh_f(float x) {
    x = fminf(fmaxf(x, -15.f), 15.f);
    float e = __expf(2.f * x);
    return (e - 1.f) * rcp_f(e + 1.f);
}
__device__ __forceinline__ unsigned short f32_bf16_rtne(float f) {
    unsigned int u = __float_as_uint(f);
    unsigned int r = u + 0x7fffu + ((u >> 16) & 1u);
    return (unsigned short)(r >> 16);
}
__device__ __forceinline__ float bf16_f32(unsigned short h) {
    return __uint_as_float(((unsigned int)h) << 16);
}

// ---------------- init: zero bucket cursors + stats ----------------
__global__ void init_zero(int* gcur, float* st) {
    int idx = blockIdx.x * 256 + threadIdx.x;
    if (idx < NBUK * 16) gcur[idx] = 0;
    if (blockIdx.x == 0 && threadIdx.x < 128) st[threadIdx.x] = 0.f;
}

// ---------------- w_ih pre-transpose: wT[h][d][g] = w_ih[h*128+g][d] ----------------
__global__ void transpose_wih(const float* __restrict__ w_ih, float* __restrict__ wT) {
    int i = blockIdx.x * 256 + threadIdx.x;   // 0..16383
    int g = i >> 6, d = i & 63;
    float v = w_ih[i];
    int h = g >> 7, gl = g & 127;
    wT[h * 8192 + d * 128 + gl] = v;
}

// ---------------- normalization stats ----------------
__global__ __launch_bounds__(256) void col_sums(const float* __restrict__ x, float* __restrict__ st) {
    int c = threadIdx.x & 63;
    size_t i = (size_t)blockIdx.x * 256 + threadIdx.x;
    size_t stride = (size_t)gridDim.x * 256;
    float s = 0.f, q = 0.f;
    for (size_t e = i; e < (size_t)NN * 64; e += stride) {
        float v = x[e]; s += v; q = fmaf(v, v, q);
    }
    __shared__ float ls[128];
    if (threadIdx.x < 128) ls[threadIdx.x] = 0.f;
    __syncthreads();
    atomicAdd(&ls[c], s); atomicAdd(&ls[64 + c], q);
    __syncthreads();
    if (threadIdx.x < 128) atomicAdd(&st[threadIdx.x], ls[threadIdx.x]);
}

__global__ void finalize_stats(float* st) {
    int c = threadIdx.x;
    if (c < 64) {
        float s = st[c], q = st[64 + c];
        float mean = s / (float)NN;
        float var = (q - s * s / (float)NN) / (float)(NN - 1);
        st[128 + c] = mean;
        st[192 + c] = rsqrtf(fmaxf(var, 1e-20f));
    }
}

// ---------------- xnd = dis[n] * normalize(x[n]) ----------------
// Removes the per-edge dis[src] load + per-edge normalization from gather-1
// (R10 post-mortem: gather is latency-bound on its per-edge load chain).
__global__ __launch_bounds__(256) void xnd_kernel(const float* __restrict__ x, const float* __restrict__ st,
                                                  const float* __restrict__ dis, float* __restrict__ xnd) {
    size_t i = (size_t)blockIdx.x * 256 + threadIdx.x;   // float4 index
    int n = (int)(i >> 4), q = (int)(i & 15);
    float4 v = ((const float4*)x)[i];
    float4 mean4 = ((const float4*)(st + 128))[q];
    float4 istd4 = ((const float4*)(st + 192))[q];
    float dn = dis[n];
    v.x = (v.x - mean4.x) * istd4.x * dn;
    v.y = (v.y - mean4.y) * istd4.y * dn;
    v.z = (v.z - mean4.z) * istd4.z * dn;
    v.w = (v.w - mean4.w) * istd4.w * dn;
    ((float4*)xnd)[i] = v;
}

// ---------------- pass 1: coarse bucket partition (contiguous block-local runs) ----------------
// Entry staging format: meta = src | (dst&255)<<24 (src < 2^17), w = |ea| bits.
__global__ __launch_bounds__(256) void part_kernel(const int* __restrict__ ei, const float* __restrict__ ea,
                                                   int* __restrict__ gcur, int2* __restrict__ ent2) {
    __shared__ int lhist[NBUK];
    __shared__ int lbase[NBUK];
    const int tid = threadIdx.x;
    const int e0 = blockIdx.x * PCHUNK;
    for (int i = tid; i < NBUK; i += 256) lhist[i] = 0;
    __syncthreads();
    #pragma unroll 4
    for (int i = 0; i < PCHUNK / 256; ++i) {
        int d = ei[EE + e0 + i * 256 + tid];
        atomicAdd(&lhist[d >> 8], 1);
    }
    __syncthreads();
    // reserve one contiguous range per bucket (gcur padded: 1 counter / 64B line)
    for (int i = tid; i < NBUK; i += 256) {
        lbase[i] = atomicAdd(&gcur[i * 16], lhist[i]);
        lhist[i] = 0;
    }
    __syncthreads();
    for (int i = 0; i < PCHUNK / 256; ++i) {
        int e = e0 + i * 256 + tid;
        int d = ei[EE + e];
        int s = ei[e];
        float w = fabsf(ea[2 * (size_t)e]);
        int b = d >> 8;
        int local = atomicAdd(&lhist[b], 1);
        int pos = lbase[b] + local;
        if (pos < BCAP)
            ent2[(size_t)b * BCAP + pos] = make_int2(s | ((d & 255) << 24), __float_as_int(w));
    }
}

// ---------------- pass 2: per-bucket counting sort in LDS + rng + dis ----------------
__global__ __launch_bounds__(256) void bucket_csr(const int2* __restrict__ ent2, const int* __restrict__ gcur,
                                                  int2* __restrict__ ent, int2* __restrict__ rng,
                                                  float* __restrict__ dis) {
    __shared__ int nhist[256];
    __shared__ int scn[256];
    __shared__ float wsum[256];
    __shared__ int pcur[256];
    const int tid = threadIdx.x;
    const int b = blockIdx.x;
    const int base = b * BCAP;
    int cnt = gcur[b * 16];
    if (cnt > BCAP) cnt = BCAP;
    nhist[tid] = 0;
    wsum[tid] = 0.f;
    __syncthreads();
    for (int e = tid; e < cnt; e += 256) {
        int2 en = ent2[base + e];
        int dl = ((unsigned)en.x) >> 24;
        atomicAdd(&nhist[dl], 1);
        atomicAdd(&wsum[dl], __int_as_float(en.y));
    }
    __syncthreads();
    int c = nhist[tid];
    scn[tid] = c;
    __syncthreads();
    for (int d = 1; d < 256; d <<= 1) {
        int t = (tid >= d) ? scn[tid - d] : 0;
        __syncthreads();
        scn[tid] += t;
        __syncthreads();
    }
    int ps = scn[tid] - c;                       // exclusive prefix within bucket
    rng[b * 256 + tid] = make_int2(base + ps, base + ps + c);
    dis[b * 256 + tid] = rsqrtf(1.f + wsum[tid]); // self-loop weight 1 folded in
    pcur[tid] = ps;
    __syncthreads();
    for (int e = tid; e < cnt; e += 256) {
        int2 en = ent2[base + e];
        int dl = ((unsigned)en.x) >> 24;
        int local = atomicAdd(&pcur[dl], 1);
        ent[base + local] = make_int2(en.x & 0xFFFFFF, en.y);
    }
}

// ---------------- tiled f32 GEMM ----------------
// Weights always consumed in [K][NC] layout. DISO: scale output rows by dscale[row]
// (produces pre-scaled h2d so gather-2 needs no per-edge dis load).
template<int K, int NC, int MB, int THREADS, bool PRELU, bool XGOUT, bool DISO>
__global__ __launch_bounds__(THREADS) void gemm_tiled(
    const float* __restrict__ A, const float* __restrict__ Wm,
    const float* __restrict__ bin, const float* __restrict__ bo1, const float* __restrict__ bo2,
    const float* __restrict__ dscale, float* __restrict__ Cm, int ldC)
{
    __shared__ float As[MB * K];
    __shared__ float Ws[K * NC];
    const int cb0 = XGOUT ? ((int)blockIdx.y * NC) : 0;
    const float* Wsrc = Wm + (XGOUT ? (size_t)cb0 * K : 0);

    for (int i = threadIdx.x; i < K * NC / 4; i += THREADS)
        ((float4*)Ws)[i] = ((const float4*)Wsrc)[i];

    size_t row0 = (size_t)blockIdx.x * MB;
    for (int i = threadIdx.x; i < MB * (K / 4); i += THREADS) {
        int r = i / (K / 4); int c = (i % (K / 4)) * 4;
        float4 a = *(const float4*)(A + (row0 + r) * K + c);
        if (PRELU) {
            a.x = fmaxf(a.x + bin[c + 0], 0.f); a.y = fmaxf(a.y + bin[c + 1], 0.f);
            a.z = fmaxf(a.z + bin[c + 2], 0.f); a.w = fmaxf(a.w + bin[c + 3], 0.f);
        }
        ((float4*)As)[i] = a;
    }
    __syncthreads();

    constexpr int NCT = NC / 4;
    int tc = threadIdx.x % NCT;
    int tr = threadIdx.x / NCT;
    int r = tr * 4;
    float4 acc[4];
    acc[0] = acc[1] = acc[2] = acc[3] = make_float4(0.f, 0.f, 0.f, 0.f);

    #pragma unroll 8
    for (int d4 = 0; d4 < K / 4; ++d4) {
        float4 w0 = ((const float4*)Ws)[(4 * d4 + 0) * NCT + tc];
        float4 w1 = ((const float4*)Ws)[(4 * d4 + 1) * NCT + tc];
        float4 w2 = ((const float4*)Ws)[(4 * d4 + 2) * NCT + tc];
        float4 w3 = ((const float4*)Ws)[(4 * d4 + 3) * NCT + tc];
        #pragma unroll
        for (int i = 0; i < 4; ++i) {
            float4 av = ((const float4*)As)[(r + i) * (K / 4) + d4];
            fma4(acc[i], av.x, w0); fma4(acc[i], av.y, w1);
            fma4(acc[i], av.z, w2); fma4(acc[i], av.w, w3);
        }
    }

    if (!XGOUT) {
        #pragma unroll
        for (int i = 0; i < 4; ++i) {
            size_t row = row0 + r + i;
            float4 o = acc[i];
            if (DISO) {
                float dn = dscale[row];
                o.x *= dn; o.y *= dn; o.z *= dn; o.w *= dn;
            }
            *(float4*)(Cm + row * ldC + tc * 4) = o;
        }
    } else {
        int cb = cb0 + tc * 4;
        float4 bs;
        bs.x = bo1[cb + 0] + bo2[cb + 0]; bs.y = bo1[cb + 1] + bo2[cb + 1];
        bs.z = bo1[cb + 2] + bo2[cb + 2]; bs.w = bo1[cb + 3] + bo2[cb + 3];
        #pragma unroll
        for (int i = 0; i < 4; ++i) {
            int n = (int)row0 + r + i;                      // n = b*T*NODES + t*NODES + node
            int b_ = n / (TT * NODESC);
            int rem = n - b_ * (TT * NODESC);
            int t = rem / NODESC;
            int node = rem - t * NODESC;
            int orow = (b_ * NODESC + node) * TT + t;       // seq-major, time inner
            float4 o = acc[i];
            o.x += bs.x; o.y += bs.y; o.z += bs.z; o.w += bs.w;
            *(float4*)(Cm + (size_t)orow * ldC + cb) = o;
        }
    }
}

// ---------------- GCN aggregation: gather over packed CSR (rng int2 ranges) ----------------
// Input h is pre-scaled by dis (xnd / h2d), so per edge: one 8B ent load + one
// random 16B row load, 4x unrolled for MLP. g[n] = dis[n]*(h[n] + sum w_e*h[src]).
template<int C4>
__global__ __launch_bounds__(256) void gcn_gather(const float* __restrict__ h, const int2* __restrict__ rng,
                                                  const int2* __restrict__ ent, const float* __restrict__ dis,
                                                  float* __restrict__ g) {
    unsigned int idx = blockIdx.x * 256 + threadIdx.x;
    unsigned int n = idx / C4, q = idx % C4;
    float4 acc = ((const float4*)h)[(size_t)n * C4 + q];
    int2 r = rng[n];
    int e = r.x;
    for (; e + 4 <= r.y; e += 4) {
        int2 en0 = ent[e], en1 = ent[e + 1], en2 = ent[e + 2], en3 = ent[e + 3];
        float4 v0 = ((const float4*)h)[(size_t)en0.x * C4 + q];
        float4 v1 = ((const float4*)h)[(size_t)en1.x * C4 + q];
        float4 v2 = ((const float4*)h)[(size_t)en2.x * C4 + q];
        float4 v3 = ((const float4*)h)[(size_t)en3.x * C4 + q];
        fma4(acc, __int_as_float(en0.y), v0);
        fma4(acc, __int_as_float(en1.y), v1);
        fma4(acc, __int_as_float(en2.y), v2);
        fma4(acc, __int_as_float(en3.y), v3);
    }
    for (; e < r.y; ++e) {
        int2 en = ent[e];
        float4 v = ((const float4*)h)[(size_t)en.x * C4 + q];
        fma4(acc, __int_as_float(en.y), v);
    }
    float dn = dis[n];
    acc.x *= dn; acc.y *= dn; acc.z *= dn; acc.w *= dn;
    ((float4*)g)[(size_t)n * C4 + q] = acc;
}

// ---------------- LSTM (recurrent part; xg precomputed) ----------------
// MFMA path (R8): per step, gates[16 seqs x 256 rows] = h[16x64] @ whh^T via
// mfma_f32_16x16x32_bf16 with hi/lo bf16 split (3 MFMAs, err ~2^-18).
#define HP_LD 66   // hpack row stride (uints)
#define GP_LD 257  // gp row stride (floats)

__global__ __launch_bounds__(1024, 1) void lstm_kernel(const float* __restrict__ xg, const float* __restrict__ whh,
                                                       float* __restrict__ hlast) {
    __shared__ __align__(16) unsigned int hpack[16 * HP_LD];  // h as bf16 hi|lo
    __shared__ float gp[16 * GP_LD];                          // gate pre-activations
    const int tid  = threadIdx.x;       // 0..1023
    const int lane = tid & 63;
    const int wv   = tid >> 6;          // wave 0..15 = gate tile (dot) and seq (act)
    const int n15  = lane & 15;         // A: seq m / B: gate-in-tile n
    const int quad = lane >> 4;         // k sub-block
    const int gate = wv * 16 + n15;
    const int qa   = wv;                // activation seq 0..15
    const int ja   = lane;              // activation hidden unit 0..63

    // ---- loop-invariant B-frags: w_hh row `gate`, bf16 hi/lo split ----
    s16x8 bhi0, bhi1, blo0, blo1;
    {
        const float* wp0 = whh + (size_t)gate * 64 + 0 * 32 + quad * 8;
        const float* wp1 = whh + (size_t)gate * 64 + 1 * 32 + quad * 8;
        #pragma unroll
        for (int j = 0; j < 8; ++j) {
            float w0 = wp0[j], w1 = wp1[j];
            unsigned short h0 = f32_bf16_rtne(w0);
            unsigned short h1 = f32_bf16_rtne(w1);
            bhi0[j] = (short)h0; blo0[j] = (short)f32_bf16_rtne(w0 - bf16_f32(h0));
            bhi1[j] = (short)h1; blo1[j] = (short)f32_bf16_rtne(w1 - bf16_f32(h1));
        }
    }

    // ---- init h = 0, prefetch first xg gate inputs ----
    for (int i = tid; i < 16 * HP_LD; i += 1024) hpack[i] = 0u;
    float c_reg = 0.f, hn = 0.f;
    const float* xa = xg + ((size_t)blockIdx.x * 16 + qa) * TT * G4 + ja;
    float xi = xa[0], xf = xa[64], xgv = xa[128], xo = xa[192];
    __syncthreads();

    for (int t = 0; t < TT; ++t) {
        // prefetch next step's gate inputs
        const int tn = (t + 1 < TT) ? t + 1 : t;
        const float* xan = xa + tn * G4;
        float ni = xan[0], nf = xan[64], ng = xan[128], no = xan[192];

        // ---- dot phase: 6 MFMAs ----
        f32x4 c = {0.f, 0.f, 0.f, 0.f};
        #pragma unroll
        for (int kc = 0; kc < 2; ++kc) {
            const uint2* hp = (const uint2*)(hpack + n15 * HP_LD + kc * 32 + quad * 8);
            uint2 p0 = hp[0], p1 = hp[1], p2 = hp[2], p3 = hp[3];
            s16x8 ahi, alo;
            ahi[0] = (short)(p0.x & 0xffff); alo[0] = (short)(p0.x >> 16);
            ahi[1] = (short)(p0.y & 0xffff); alo[1] = (short)(p0.y >> 16);
            ahi[2] = (short)(p1.x & 0xffff); alo[2] = (short)(p1.x >> 16);
            ahi[3] = (short)(p1.y & 0xffff); alo[3] = (short)(p1.y >> 16);
            ahi[4] = (short)(p2.x & 0xffff); alo[4] = (short)(p2.x >> 16);
            ahi[5] = (short)(p2.y & 0xffff); alo[5] = (short)(p2.y >> 16);
            ahi[6] = (short)(p3.x & 0xffff); alo[6] = (short)(p3.x >> 16);
            ahi[7] = (short)(p3.y & 0xffff); alo[7] = (short)(p3.y >> 16);
            const s16x8 bh = kc ? bhi1 : bhi0;
            const s16x8 bl = kc ? blo1 : blo0;
            c = __builtin_amdgcn_mfma_f32_16x16x32_bf16(ahi, bh, c, 0, 0, 0);
            c = __builtin_amdgcn_mfma_f32_16x16x32_bf16(alo, bh, c, 0, 0, 0);
            c = __builtin_amdgcn_mfma_f32_16x16x32_bf16(ahi, bl, c, 0, 0, 0);
        }
        // C: lane holds seqs m = quad*4+r, gate column `gate`
        #pragma unroll
        for (int r = 0; r < 4; ++r)
            gp[(quad * 4 + r) * GP_LD + gate] = c[r];
        __syncthreads();

        // ---- activation phase: thread (qa, ja) ----
        {
            float gi = gp[qa * GP_LD + ja]        + xi;
            float gf = gp[qa * GP_LD + 64 + ja]   + xf;
            float gg = gp[qa * GP_LD + 128 + ja]  + xgv;
            float go = gp[qa * GP_LD + 192 + ja]  + xo;
            c_reg = sigm_f(gf) * c_reg + sigm_f(gi) * tanh_f(gg);
            hn = sigm_f(go) * tanh_f(c_reg);
            unsigned short hh = f32_bf16_rtne(hn);
            unsigned short hl = f32_bf16_rtne(hn - bf16_f32(hh));
            hpack[qa * HP_LD + ja] = (unsigned int)hh | ((unsigned int)hl << 16);
        }
        __syncthreads();
        xi = ni; xf = nf; xgv = ng; xo = no;
    }
    hlast[((size_t)blockIdx.x * 16 + qa) * 64 + ja] = hn;
}

// ---------------- FC head + softmax ----------------
__global__ __launch_bounds__(128) void head_kernel(const float* __restrict__ hl,
                                                   const float* __restrict__ w1, const float* __restrict__ b1,
                                                   const float* __restrict__ w2, const float* __restrict__ b2,
                                                   float* __restrict__ out) {
    __shared__ float hrow[64];
    __shared__ float a1[128];
    __shared__ float lg[3];
    int s = blockIdx.x, tid = threadIdx.x;
    if (tid < 64) hrow[tid] = hl[(size_t)s * 64 + tid];
    __syncthreads();
    {
        const float4* wr = (const float4*)(w1 + (size_t)tid * 64);
        const float4* hq = (const float4*)hrow;
        float4 acc = make_float4(0.f, 0.f, 0.f, 0.f);
        #pragma unroll
        for (int k = 0; k < 16; ++k) {
            float4 wv = wr[k]; float4 hv = hq[k];
            acc.x = fmaf(wv.x, hv.x, acc.x); acc.y = fmaf(wv.y, hv.y, acc.y);
            acc.z = fmaf(wv.z, hv.z, acc.z); acc.w = fmaf(wv.w, hv.w, acc.w);
        }
        a1[tid] = fmaxf((acc.x + acc.y) + (acc.z + acc.w) + b1[tid], 0.f);
    }
    __syncthreads();
    if (tid < 3) {
        const float4* wr = (const float4*)(w2 + (size_t)tid * 128);
        const float4* aq = (const float4*)a1;
        float4 acc = make_float4(0.f, 0.f, 0.f, 0.f);
        #pragma unroll
        for (int k = 0; k < 32; ++k) {
            float4 wv = wr[k]; float4 av = aq[k];
            acc.x = fmaf(wv.x, av.x, acc.x); acc.y = fmaf(wv.y, av.y, acc.y);
            acc.z = fmaf(wv.z, av.z, acc.z); acc.w = fmaf(wv.w, av.w, acc.w);
        }
        lg[tid] = (acc.x + acc.y) + (acc.z + acc.w) + b2[tid];
    }
    __syncthreads();
    if (tid == 0) {
        float m = fmaxf(lg[0], fmaxf(lg[1], lg[2]));
        float e0 = __expf(lg[0] - m), e1 = __expf(lg[1] - m), e2 = __expf(lg[2] - m);
        float inv = 1.f / (e0 + e1 + e2);
        out[(size_t)s * 3 + 0] = e0 * inv;
        out[(size_t)s * 3 + 1] = e1 * inv;
        out[(size_t)s * 3 + 2] = e2 * inv;
    }
}

extern "C" void kernel_launch(void* const* d_in, const int* in_sizes, int n_in,
                              void* d_out, int out_size, void* d_ws, size_t ws_size,
                              hipStream_t stream) {
    (void)in_sizes; (void)n_in; (void)out_size; (void)ws_size;
    const float* x        = (const float*)d_in[0];
    const float* ea       = (const float*)d_in[1];
    const float* conv1_w  = (const float*)d_in[2];
    const float* conv1_b  = (const float*)d_in[3];
    const float* conv2_w  = (const float*)d_in[4];
    const float* conv2_b  = (const float*)d_in[5];
    const float* w_ih     = (const float*)d_in[6];
    const float* w_hh     = (const float*)d_in[7];
    const float* b_ih     = (const float*)d_in[8];
    const float* b_hh     = (const float*)d_in[9];
    const float* fc1_w    = (const float*)d_in[10];
    const float* fc1_b    = (const float*)d_in[11];
    const float* fc2_w    = (const float*)d_in[12];
    const float* fc2_b    = (const float*)d_in[13];
    const int*   ei       = (const int*)d_in[14];
    float* out = (float*)d_out;

    float* W    = (float*)d_ws;
    int2*  ent  = (int2*)(W + OFF_ENT);
    float* a1   = W + OFF_A1;
    float* g1   = W + OFF_G1;
    float* xg   = W + OFF_XG;
    int2*  ent2 = (int2*)(W + OFF_ENT2);
    float* xnd  = W + OFF_ENT2;          // reuses dead csr staging (then dies before h2d)
    float* h2   = W + OFF_H2;            // h2d: dis-scaled GEMM2 output
    float* g2   = W + OFF_G2;
    int*   gcur = (int*)(W + OFF_GCUR);
    float* dis  = W + OFF_DIS;
    int2*  rng  = (int2*)(W + OFF_RNG);
    float* hl   = W + OFF_HL;
    float* st   = W + OFF_ST;
    float* wT   = W + OFF_WT;

    // init + normalization stats
    init_zero<<<26, 256, 0, stream>>>(gcur, st);
    transpose_wih<<<64, 256, 0, stream>>>(w_ih, wT);
    col_sums<<<1024, 256, 0, stream>>>(x, st);
    finalize_stats<<<1, 64, 0, stream>>>(st);

    // dest-sorted CSR via two-pass counting sort (coalesced writes, no global float atomics)
    part_kernel<<<NPART, 256, 0, stream>>>(ei, ea, gcur, ent2);
    bucket_csr<<<NBUK, 256, 0, stream>>>(ent2, gcur, ent, rng, dis);

    // pre-scaled node features: xnd = dis * normalize(x)   (overwrites dead ent2)
    xnd_kernel<<<NN * 16 / 256, 256, 0, stream>>>(x, st, dis, xnd);

    // GCN layer 1, commuted: a1 = S·xn (64 cols), then g1 = a1 @ W1 (96 cols)
    gcn_gather<16><<<NN * 16 / 256, 256, 0, stream>>>(xnd, rng, ent, dis, a1);
    gemm_tiled<64, 96, 32, 192, false, false, false><<<NN / 32, 192, 0, stream>>>(
        a1, conv1_w, nullptr, nullptr, nullptr, nullptr, g1, 96);

    // GCN layer 2: h2d = dis * (relu(g1+b1) @ W2), then g2 = S·h2
    gemm_tiled<96, 64, 64, 256, true, false, true><<<NN / 64, 256, 0, stream>>>(
        g1, conv2_w, conv1_b, nullptr, nullptr, dis, h2, 64);
    gcn_gather<16><<<NN * 16 / 256, 256, 0, stream>>>(h2, rng, ent, dis, g2);

    // LSTM input transform: xg = relu(g2+b2) @ w_ih^T + b_ih + b_hh
    gemm_tiled<64, 128, 32, 256, true, true, false><<<dim3(NN / 32, 2), 256, 0, stream>>>(
        g2, wT, conv2_b, b_ih, b_hh, nullptr, xg, 256);

    // LSTM recurrence: MFMA path, 16 seqs/block, 1024 threads
    lstm_kernel<<<SS / 16, 1024, 0, stream>>>(xg, w_hh, hl);

    // FC head + softmax
    head_kernel<<<SS, 128, 0, stream>>>(hl, fc1_w, fc1_b, fc2_w, fc2_b, out);
}

// Round 12
// 452.295 us; speedup vs baseline: 1.4400x; 1.1071x over previous
//
#include <hip/hip_runtime.h>
#include <hip/hip_bf16.h>

#define NN 102400      // B*T*NODES
#define DD 64
#define EE 1638400
#define L1C 96
#define L2C 64
#define TT 32
#define NODESC 400
#define BB 8
#define SS 3200        // B*NODES
#define G4 256         // 4*D

#define NBUK 400       // coarse buckets (node >> 8), NN = 400*256 exactly
#define BCAP 5120      // slots per bucket (mean 4096, sd 64 -> +16 sigma)
#define PCHUNK 8192
#define NPART (EE / PCHUNK)   // 200

// ---------------- workspace layout (floats) ----------------
// [0, 26,214,400): ent | a1 | g1  -> all dead before xg overwrites the region
#define OFF_ENT  ((size_t)0)          // NBUK*BCAP int2 = 4,096,000 floats
#define OFF_A1   ((size_t)4096000)    // NN*64 -> ends 10,649,600
#define OFF_G1   ((size_t)10649600)   // NN*96 -> ends 20,480,000
#define OFF_XG   ((size_t)0)          // NN*256 = 26,214,400
#define OFF_ENT2 ((size_t)26214400)   // csr staging (4,096,000); then xnd bf16; then h2d bf16
#define OFF_H2   ((size_t)26214400)   // NN*64 bf16 = 3,276,800 floats
#define OFF_G2   ((size_t)32768000)   // NN*64 -> ends 39,321,600
#define OFF_GCUR ((size_t)39321600)   // 400 cursors padded x16 ints = 6400
#define OFF_DIS  ((size_t)39328000)   // NN -> ends 39,430,400
#define OFF_RNG  ((size_t)39430400)   // NN int2 -> ends 39,635,200
#define OFF_HL   ((size_t)39635200)   // SS*64 -> ends 39,840,000
#define OFF_ST   ((size_t)39840000)   // 256 -> ends 39,840,256
#define OFF_WT   ((size_t)39840256)   // w_ih^T [2][64][128] = 16384 -> total 39,856,640 (159.4 MB)

typedef __attribute__((ext_vector_type(8))) short s16x8;   // 8 bf16 in 4 VGPRs
typedef __attribute__((ext_vector_type(4))) float f32x4;

__device__ __forceinline__ void fma4(float4& a, float s, const float4& w) {
    a.x = fmaf(s, w.x, a.x); a.y = fmaf(s, w.y, a.y);
    a.z = fmaf(s, w.z, a.z); a.w = fmaf(s, w.w, a.w);
}
__device__ __forceinline__ float rcp_f(float x) { return __builtin_amdgcn_rcpf(x); }
__device__ __forceinline__ float sigm_f(float x) {
    x = fminf(fmaxf(x, -30.f), 30.f);
    return rcp_f(1.f + __expf(-x));
}
__device__ __forceinline__ float tanh_f(float x) {
    x = fminf(fmaxf(x, -15.f), 15.f);
    float e = __expf(2.f * x);
    return (e - 1.f) * rcp_f(e + 1.f);
}
__device__ __forceinline__ unsigned short f32_bf16_rtne(float f) {
    unsigned int u = __float_as_uint(f);
    unsigned int r = u + 0x7fffu + ((u >> 16) & 1u);
    return (unsigned short)(r >> 16);
}
__device__ __forceinline__ float bf16_f32(unsigned short h) {
    return __uint_as_float(((unsigned int)h) << 16);
}
// unpack 4 packed bf16 (uint2) -> float4
__device__ __forceinline__ float4 unp4(uint2 p) {
    float4 v;
    v.x = __uint_as_float(p.x << 16);
    v.y = __uint_as_float(p.x & 0xffff0000u);
    v.z = __uint_as_float(p.y << 16);
    v.w = __uint_as_float(p.y & 0xffff0000u);
    return v;
}
__device__ __forceinline__ uint2 pk4(float4 v) {
    unsigned int u0 = ((unsigned int)f32_bf16_rtne(v.y) << 16) | f32_bf16_rtne(v.x);
    unsigned int u1 = ((unsigned int)f32_bf16_rtne(v.w) << 16) | f32_bf16_rtne(v.z);
    return make_uint2(u0, u1);
}

// ---------------- init: zero bucket cursors + stats ----------------
__global__ void init_zero(int* gcur, float* st) {
    int idx = blockIdx.x * 256 + threadIdx.x;
    if (idx < NBUK * 16) gcur[idx] = 0;
    if (blockIdx.x == 0 && threadIdx.x < 128) st[threadIdx.x] = 0.f;
}

// ---------------- w_ih pre-transpose: wT[h][d][g] = w_ih[h*128+g][d] ----------------
__global__ void transpose_wih(const float* __restrict__ w_ih, float* __restrict__ wT) {
    int i = blockIdx.x * 256 + threadIdx.x;   // 0..16383
    int g = i >> 6, d = i & 63;
    float v = w_ih[i];
    int h = g >> 7, gl = g & 127;
    wT[h * 8192 + d * 128 + gl] = v;
}

// ---------------- normalization stats ----------------
__global__ __launch_bounds__(256) void col_sums(const float* __restrict__ x, float* __restrict__ st) {
    int c = threadIdx.x & 63;
    size_t i = (size_t)blockIdx.x * 256 + threadIdx.x;
    size_t stride = (size_t)gridDim.x * 256;
    float s = 0.f, q = 0.f;
    for (size_t e = i; e < (size_t)NN * 64; e += stride) {
        float v = x[e]; s += v; q = fmaf(v, v, q);
    }
    __shared__ float ls[128];
    if (threadIdx.x < 128) ls[threadIdx.x] = 0.f;
    __syncthreads();
    atomicAdd(&ls[c], s); atomicAdd(&ls[64 + c], q);
    __syncthreads();
    if (threadIdx.x < 128) atomicAdd(&st[threadIdx.x], ls[threadIdx.x]);
}

__global__ void finalize_stats(float* st) {
    int c = threadIdx.x;
    if (c < 64) {
        float s = st[c], q = st[64 + c];
        float mean = s / (float)NN;
        float var = (q - s * s / (float)NN) / (float)(NN - 1);
        st[128 + c] = mean;
        st[192 + c] = rsqrtf(fmaxf(var, 1e-20f));
    }
}

// ---------------- xnd = bf16( dis[n] * normalize(x[n]) ) ----------------
// bf16 rows halve gather-1's random-read traffic (R11 post-mortem: gather is
// L2-miss-BW bound; 26 MB f32 table -> 13 MB bf16, requests x0.5).
__global__ __launch_bounds__(256) void xnd_kernel(const float* __restrict__ x, const float* __restrict__ st,
                                                  const float* __restrict__ dis, uint2* __restrict__ xnd) {
    size_t i = (size_t)blockIdx.x * 256 + threadIdx.x;   // float4 index
    int n = (int)(i >> 4), q = (int)(i & 15);
    float4 v = ((const float4*)x)[i];
    float4 mean4 = ((const float4*)(st + 128))[q];
    float4 istd4 = ((const float4*)(st + 192))[q];
    float dn = dis[n];
    v.x = (v.x - mean4.x) * istd4.x * dn;
    v.y = (v.y - mean4.y) * istd4.y * dn;
    v.z = (v.z - mean4.z) * istd4.z * dn;
    v.w = (v.w - mean4.w) * istd4.w * dn;
    xnd[i] = pk4(v);
}

// ---------------- pass 1: coarse bucket partition (contiguous block-local runs) ----------------
// Entry staging format: meta = src | (dst&255)<<24 (src < 2^17), w = |ea| bits.
__global__ __launch_bounds__(256) void part_kernel(const int* __restrict__ ei, const float* __restrict__ ea,
                                                   int* __restrict__ gcur, int2* __restrict__ ent2) {
    __shared__ int lhist[NBUK];
    __shared__ int lbase[NBUK];
    const int tid = threadIdx.x;
    const int e0 = blockIdx.x * PCHUNK;
    for (int i = tid; i < NBUK; i += 256) lhist[i] = 0;
    __syncthreads();
    #pragma unroll 4
    for (int i = 0; i < PCHUNK / 256; ++i) {
        int d = ei[EE + e0 + i * 256 + tid];
        atomicAdd(&lhist[d >> 8], 1);
    }
    __syncthreads();
    // reserve one contiguous range per bucket (gcur padded: 1 counter / 64B line)
    for (int i = tid; i < NBUK; i += 256) {
        lbase[i] = atomicAdd(&gcur[i * 16], lhist[i]);
        lhist[i] = 0;
    }
    __syncthreads();
    for (int i = 0; i < PCHUNK / 256; ++i) {
        int e = e0 + i * 256 + tid;
        int d = ei[EE + e];
        int s = ei[e];
        float w = fabsf(ea[2 * (size_t)e]);
        int b = d >> 8;
        int local = atomicAdd(&lhist[b], 1);
        int pos = lbase[b] + local;
        if (pos < BCAP)
            ent2[(size_t)b * BCAP + pos] = make_int2(s | ((d & 255) << 24), __float_as_int(w));
    }
}

// ---------------- pass 2: per-bucket counting sort in LDS + rng + dis ----------------
__global__ __launch_bounds__(256) void bucket_csr(const int2* __restrict__ ent2, const int* __restrict__ gcur,
                                                  int2* __restrict__ ent, int2* __restrict__ rng,
                                                  float* __restrict__ dis) {
    __shared__ int nhist[256];
    __shared__ int scn[256];
    __shared__ float wsum[256];
    __shared__ int pcur[256];
    const int tid = threadIdx.x;
    const int b = blockIdx.x;
    const int base = b * BCAP;
    int cnt = gcur[b * 16];
    if (cnt > BCAP) cnt = BCAP;
    nhist[tid] = 0;
    wsum[tid] = 0.f;
    __syncthreads();
    for (int e = tid; e < cnt; e += 256) {
        int2 en = ent2[base + e];
        int dl = ((unsigned)en.x) >> 24;
        atomicAdd(&nhist[dl], 1);
        atomicAdd(&wsum[dl], __int_as_float(en.y));
    }
    __syncthreads();
    int c = nhist[tid];
    scn[tid] = c;
    __syncthreads();
    for (int d = 1; d < 256; d <<= 1) {
        int t = (tid >= d) ? scn[tid - d] : 0;
        __syncthreads();
        scn[tid] += t;
        __syncthreads();
    }
    int ps = scn[tid] - c;                       // exclusive prefix within bucket
    rng[b * 256 + tid] = make_int2(base + ps, base + ps + c);
    dis[b * 256 + tid] = rsqrtf(1.f + wsum[tid]); // self-loop weight 1 folded in
    pcur[tid] = ps;
    __syncthreads();
    for (int e = tid; e < cnt; e += 256) {
        int2 en = ent2[base + e];
        int dl = ((unsigned)en.x) >> 24;
        int local = atomicAdd(&pcur[dl], 1);
        ent[base + local] = make_int2(en.x & 0xFFFFFF, en.y);
    }
}

// ---------------- tiled f32 GEMM ----------------
// Weights always consumed in [K][NC] layout. DISO: scale output rows by dscale[row]
// and store as packed bf16 (feeds the bf16 gather); ldC then counts ushorts.
template<int K, int NC, int MB, int THREADS, bool PRELU, bool XGOUT, bool DISO>
__global__ __launch_bounds__(THREADS) void gemm_tiled(
    const float* __restrict__ A, const float* __restrict__ Wm,
    const float* __restrict__ bin, const float* __restrict__ bo1, const float* __restrict__ bo2,
    const float* __restrict__ dscale, float* __restrict__ Cm, int ldC)
{
    __shared__ float As[MB * K];
    __shared__ float Ws[K * NC];
    const int cb0 = XGOUT ? ((int)blockIdx.y * NC) : 0;
    const float* Wsrc = Wm + (XGOUT ? (size_t)cb0 * K : 0);

    for (int i = threadIdx.x; i < K * NC / 4; i += THREADS)
        ((float4*)Ws)[i] = ((const float4*)Wsrc)[i];

    size_t row0 = (size_t)blockIdx.x * MB;
    for (int i = threadIdx.x; i < MB * (K / 4); i += THREADS) {
        int r = i / (K / 4); int c = (i % (K / 4)) * 4;
        float4 a = *(const float4*)(A + (row0 + r) * K + c);
        if (PRELU) {
            a.x = fmaxf(a.x + bin[c + 0], 0.f); a.y = fmaxf(a.y + bin[c + 1], 0.f);
            a.z = fmaxf(a.z + bin[c + 2], 0.f); a.w = fmaxf(a.w + bin[c + 3], 0.f);
        }
        ((float4*)As)[i] = a;
    }
    __syncthreads();

    constexpr int NCT = NC / 4;
    int tc = threadIdx.x % NCT;
    int tr = threadIdx.x / NCT;
    int r = tr * 4;
    float4 acc[4];
    acc[0] = acc[1] = acc[2] = acc[3] = make_float4(0.f, 0.f, 0.f, 0.f);

    #pragma unroll 8
    for (int d4 = 0; d4 < K / 4; ++d4) {
        float4 w0 = ((const float4*)Ws)[(4 * d4 + 0) * NCT + tc];
        float4 w1 = ((const float4*)Ws)[(4 * d4 + 1) * NCT + tc];
        float4 w2 = ((const float4*)Ws)[(4 * d4 + 2) * NCT + tc];
        float4 w3 = ((const float4*)Ws)[(4 * d4 + 3) * NCT + tc];
        #pragma unroll
        for (int i = 0; i < 4; ++i) {
            float4 av = ((const float4*)As)[(r + i) * (K / 4) + d4];
            fma4(acc[i], av.x, w0); fma4(acc[i], av.y, w1);
            fma4(acc[i], av.z, w2); fma4(acc[i], av.w, w3);
        }
    }

    if (!XGOUT) {
        #pragma unroll
        for (int i = 0; i < 4; ++i) {
            size_t row = row0 + r + i;
            float4 o = acc[i];
            if (DISO) {
                float dn = dscale[row];
                o.x *= dn; o.y *= dn; o.z *= dn; o.w *= dn;
                *(uint2*)((unsigned short*)Cm + row * ldC + tc * 4) = pk4(o);
            } else {
                *(float4*)(Cm + row * ldC + tc * 4) = o;
            }
        }
    } else {
        int cb = cb0 + tc * 4;
        float4 bs;
        bs.x = bo1[cb + 0] + bo2[cb + 0]; bs.y = bo1[cb + 1] + bo2[cb + 1];
        bs.z = bo1[cb + 2] + bo2[cb + 2]; bs.w = bo1[cb + 3] + bo2[cb + 3];
        #pragma unroll
        for (int i = 0; i < 4; ++i) {
            int n = (int)row0 + r + i;                      // n = b*T*NODES + t*NODES + node
            int b_ = n / (TT * NODESC);
            int rem = n - b_ * (TT * NODESC);
            int t = rem / NODESC;
            int node = rem - t * NODESC;
            int orow = (b_ * NODESC + node) * TT + t;       // seq-major, time inner
            float4 o = acc[i];
            o.x += bs.x; o.y += bs.y; o.z += bs.z; o.w += bs.w;
            *(float4*)(Cm + (size_t)orow * ldC + cb) = o;
        }
    }
}

// ---------------- GCN aggregation: gather over packed CSR (rng int2 ranges) ----------------
// Input h rows are dis-prescaled bf16 (4 packed per uint2). Per edge per thread:
// one 8B ent load + one random 8B row-chunk load, 8x/4x unrolled for MLP.
// g[n] = dis[n]*(h[n] + sum w_e*h[src]),  f32 accumulate and output.
template<int C4>
__global__ __launch_bounds__(256) void gcn_gather(const uint2* __restrict__ h, const int2* __restrict__ rng,
                                                  const int2* __restrict__ ent, const float* __restrict__ dis,
                                                  float* __restrict__ g) {
    unsigned int idx = blockIdx.x * 256 + threadIdx.x;
    unsigned int n = idx / C4, q = idx % C4;
    float4 acc = unp4(h[(size_t)n * C4 + q]);
    int2 r = rng[n];
    int e = r.x;
    for (; e + 8 <= r.y; e += 8) {
        int2 en0 = ent[e],     en1 = ent[e + 1], en2 = ent[e + 2], en3 = ent[e + 3];
        int2 en4 = ent[e + 4], en5 = ent[e + 5], en6 = ent[e + 6], en7 = ent[e + 7];
        uint2 v0 = h[(size_t)en0.x * C4 + q];
        uint2 v1 = h[(size_t)en1.x * C4 + q];
        uint2 v2 = h[(size_t)en2.x * C4 + q];
        uint2 v3 = h[(size_t)en3.x * C4 + q];
        uint2 v4 = h[(size_t)en4.x * C4 + q];
        uint2 v5 = h[(size_t)en5.x * C4 + q];
        uint2 v6 = h[(size_t)en6.x * C4 + q];
        uint2 v7 = h[(size_t)en7.x * C4 + q];
        fma4(acc, __int_as_float(en0.y), unp4(v0));
        fma4(acc, __int_as_float(en1.y), unp4(v1));
        fma4(acc, __int_as_float(en2.y), unp4(v2));
        fma4(acc, __int_as_float(en3.y), unp4(v3));
        fma4(acc, __int_as_float(en4.y), unp4(v4));
        fma4(acc, __int_as_float(en5.y), unp4(v5));
        fma4(acc, __int_as_float(en6.y), unp4(v6));
        fma4(acc, __int_as_float(en7.y), unp4(v7));
    }
    for (; e + 4 <= r.y; e += 4) {
        int2 en0 = ent[e], en1 = ent[e + 1], en2 = ent[e + 2], en3 = ent[e + 3];
        uint2 v0 = h[(size_t)en0.x * C4 + q];
        uint2 v1 = h[(size_t)en1.x * C4 + q];
        uint2 v2 = h[(size_t)en2.x * C4 + q];
        uint2 v3 = h[(size_t)en3.x * C4 + q];
        fma4(acc, __int_as_float(en0.y), unp4(v0));
        fma4(acc, __int_as_float(en1.y), unp4(v1));
        fma4(acc, __int_as_float(en2.y), unp4(v2));
        fma4(acc, __int_as_float(en3.y), unp4(v3));
    }
    for (; e < r.y; ++e) {
        int2 en = ent[e];
        uint2 v = h[(size_t)en.x * C4 + q];
        fma4(acc, __int_as_float(en.y), unp4(v));
    }
    float dn = dis[n];
    acc.x *= dn; acc.y *= dn; acc.z *= dn; acc.w *= dn;
    ((float4*)g)[(size_t)n * C4 + q] = acc;
}

// ---------------- LSTM (recurrent part; xg precomputed) ----------------
// MFMA path (R8): per step, gates[16 seqs x 256 rows] = h[16x64] @ whh^T via
// mfma_f32_16x16x32_bf16 with hi/lo bf16 split (3 MFMAs, err ~2^-18).
#define HP_LD 66   // hpack row stride (uints)
#define GP_LD 257  // gp row stride (floats)

__global__ __launch_bounds__(1024, 1) void lstm_kernel(const float* __restrict__ xg, const float* __restrict__ whh,
                                                       float* __restrict__ hlast) {
    __shared__ __align__(16) unsigned int hpack[16 * HP_LD];  // h as bf16 hi|lo
    __shared__ float gp[16 * GP_LD];                          // gate pre-activations
    const int tid  = threadIdx.x;       // 0..1023
    const int lane = tid & 63;
    const int wv   = tid >> 6;          // wave 0..15 = gate tile (dot) and seq (act)
    const int n15  = lane & 15;         // A: seq m / B: gate-in-tile n
    const int quad = lane >> 4;         // k sub-block
    const int gate = wv * 16 + n15;
    const int qa   = wv;                // activation seq 0..15
    const int ja   = lane;              // activation hidden unit 0..63

    // ---- loop-invariant B-frags: w_hh row `gate`, bf16 hi/lo split ----
    s16x8 bhi0, bhi1, blo0, blo1;
    {
        const float* wp0 = whh + (size_t)gate * 64 + 0 * 32 + quad * 8;
        const float* wp1 = whh + (size_t)gate * 64 + 1 * 32 + quad * 8;
        #pragma unroll
        for (int j = 0; j < 8; ++j) {
            float w0 = wp0[j], w1 = wp1[j];
            unsigned short h0 = f32_bf16_rtne(w0);
            unsigned short h1 = f32_bf16_rtne(w1);
            bhi0[j] = (short)h0; blo0[j] = (short)f32_bf16_rtne(w0 - bf16_f32(h0));
            bhi1[j] = (short)h1; blo1[j] = (short)f32_bf16_rtne(w1 - bf16_f32(h1));
        }
    }

    // ---- init h = 0, prefetch first xg gate inputs ----
    for (int i = tid; i < 16 * HP_LD; i += 1024) hpack[i] = 0u;
    float c_reg = 0.f, hn = 0.f;
    const float* xa = xg + ((size_t)blockIdx.x * 16 + qa) * TT * G4 + ja;
    float xi = xa[0], xf = xa[64], xgv = xa[128], xo = xa[192];
    __syncthreads();

    for (int t = 0; t < TT; ++t) {
        // prefetch next step's gate inputs
        const int tn = (t + 1 < TT) ? t + 1 : t;
        const float* xan = xa + tn * G4;
        float ni = xan[0], nf = xan[64], ng = xan[128], no = xan[192];

        // ---- dot phase: 6 MFMAs ----
        f32x4 c = {0.f, 0.f, 0.f, 0.f};
        #pragma unroll
        for (int kc = 0; kc < 2; ++kc) {
            const uint2* hp = (const uint2*)(hpack + n15 * HP_LD + kc * 32 + quad * 8);
            uint2 p0 = hp[0], p1 = hp[1], p2 = hp[2], p3 = hp[3];
            s16x8 ahi, alo;
            ahi[0] = (short)(p0.x & 0xffff); alo[0] = (short)(p0.x >> 16);
            ahi[1] = (short)(p0.y & 0xffff); alo[1] = (short)(p0.y >> 16);
            ahi[2] = (short)(p1.x & 0xffff); alo[2] = (short)(p1.x >> 16);
            ahi[3] = (short)(p1.y & 0xffff); alo[3] = (short)(p1.y >> 16);
            ahi[4] = (short)(p2.x & 0xffff); alo[4] = (short)(p2.x >> 16);
            ahi[5] = (short)(p2.y & 0xffff); alo[5] = (short)(p2.y >> 16);
            ahi[6] = (short)(p3.x & 0xffff); alo[6] = (short)(p3.x >> 16);
            ahi[7] = (short)(p3.y & 0xffff); alo[7] = (short)(p3.y >> 16);
            const s16x8 bh = kc ? bhi1 : bhi0;
            const s16x8 bl = kc ? blo1 : blo0;
            c = __builtin_amdgcn_mfma_f32_16x16x32_bf16(ahi, bh, c, 0, 0, 0);
            c = __builtin_amdgcn_mfma_f32_16x16x32_bf16(alo, bh, c, 0, 0, 0);
            c = __builtin_amdgcn_mfma_f32_16x16x32_bf16(ahi, bl, c, 0, 0, 0);
        }
        // C: lane holds seqs m = quad*4+r, gate column `gate`
        #pragma unroll
        for (int r = 0; r < 4; ++r)
            gp[(quad * 4 + r) * GP_LD + gate] = c[r];
        __syncthreads();

        // ---- activation phase: thread (qa, ja) ----
        {
            float gi = gp[qa * GP_LD + ja]        + xi;
            float gf = gp[qa * GP_LD + 64 + ja]   + xf;
            float gg = gp[qa * GP_LD + 128 + ja]  + xgv;
            float go = gp[qa * GP_LD + 192 + ja]  + xo;
            c_reg = sigm_f(gf) * c_reg + sigm_f(gi) * tanh_f(gg);
            hn = sigm_f(go) * tanh_f(c_reg);
            unsigned short hh = f32_bf16_rtne(hn);
            unsigned short hl = f32_bf16_rtne(hn - bf16_f32(hh));
            hpack[qa * HP_LD + ja] = (unsigned int)hh | ((unsigned int)hl << 16);
        }
        __syncthreads();
        xi = ni; xf = nf; xgv = ng; xo = no;
    }
    hlast[((size_t)blockIdx.x * 16 + qa) * 64 + ja] = hn;
}

// ---------------- FC head + softmax ----------------
__global__ __launch_bounds__(128) void head_kernel(const float* __restrict__ hl,
                                                   const float* __restrict__ w1, const float* __restrict__ b1,
                                                   const float* __restrict__ w2, const float* __restrict__ b2,
                                                   float* __restrict__ out) {
    __shared__ float hrow[64];
    __shared__ float a1[128];
    __shared__ float lg[3];
    int s = blockIdx.x, tid = threadIdx.x;
    if (tid < 64) hrow[tid] = hl[(size_t)s * 64 + tid];
    __syncthreads();
    {
        const float4* wr = (const float4*)(w1 + (size_t)tid * 64);
        const float4* hq = (const float4*)hrow;
        float4 acc = make_float4(0.f, 0.f, 0.f, 0.f);
        #pragma unroll
        for (int k = 0; k < 16; ++k) {
            float4 wv = wr[k]; float4 hv = hq[k];
            acc.x = fmaf(wv.x, hv.x, acc.x); acc.y = fmaf(wv.y, hv.y, acc.y);
            acc.z = fmaf(wv.z, hv.z, acc.z); acc.w = fmaf(wv.w, hv.w, acc.w);
        }
        a1[tid] = fmaxf((acc.x + acc.y) + (acc.z + acc.w) + b1[tid], 0.f);
    }
    __syncthreads();
    if (tid < 3) {
        const float4* wr = (const float4*)(w2 + (size_t)tid * 128);
        const float4* aq = (const float4*)a1;
        float4 acc = make_float4(0.f, 0.f, 0.f, 0.f);
        #pragma unroll
        for (int k = 0; k < 32; ++k) {
            float4 wv = wr[k]; float4 av = aq[k];
            acc.x = fmaf(wv.x, av.x, acc.x); acc.y = fmaf(wv.y, av.y, acc.y);
            acc.z = fmaf(wv.z, av.z, acc.z); acc.w = fmaf(wv.w, av.w, acc.w);
        }
        lg[tid] = (acc.x + acc.y) + (acc.z + acc.w) + b2[tid];
    }
    __syncthreads();
    if (tid == 0) {
        float m = fmaxf(lg[0], fmaxf(lg[1], lg[2]));
        float e0 = __expf(lg[0] - m), e1 = __expf(lg[1] - m), e2 = __expf(lg[2] - m);
        float inv = 1.f / (e0 + e1 + e2);
        out[(size_t)s * 3 + 0] = e0 * inv;
        out[(size_t)s * 3 + 1] = e1 * inv;
        out[(size_t)s * 3 + 2] = e2 * inv;
    }
}

extern "C" void kernel_launch(void* const* d_in, const int* in_sizes, int n_in,
                              void* d_out, int out_size, void* d_ws, size_t ws_size,
                              hipStream_t stream) {
    (void)in_sizes; (void)n_in; (void)out_size; (void)ws_size;
    const float* x        = (const float*)d_in[0];
    const float* ea       = (const float*)d_in[1];
    const float* conv1_w  = (const float*)d_in[2];
    const float* conv1_b  = (const float*)d_in[3];
    const float* conv2_w  = (const float*)d_in[4];
    const float* conv2_b  = (const float*)d_in[5];
    const float* w_ih     = (const float*)d_in[6];
    const float* w_hh     = (const float*)d_in[7];
    const float* b_ih     = (const float*)d_in[8];
    const float* b_hh     = (const float*)d_in[9];
    const float* fc1_w    = (const float*)d_in[10];
    const float* fc1_b    = (const float*)d_in[11];
    const float* fc2_w    = (const float*)d_in[12];
    const float* fc2_b    = (const float*)d_in[13];
    const int*   ei       = (const int*)d_in[14];
    float* out = (float*)d_out;

    float* W    = (float*)d_ws;
    int2*  ent  = (int2*)(W + OFF_ENT);
    float* a1   = W + OFF_A1;
    float* g1   = W + OFF_G1;
    float* xg   = W + OFF_XG;
    int2*  ent2 = (int2*)(W + OFF_ENT2);
    uint2* xnd  = (uint2*)(W + OFF_ENT2);  // bf16 rows; reuses dead csr staging
    float* h2   = W + OFF_H2;              // bf16 rows (cast at use); overwrites dead xnd
    float* g2   = W + OFF_G2;
    int*   gcur = (int*)(W + OFF_GCUR);
    float* dis  = W + OFF_DIS;
    int2*  rng  = (int2*)(W + OFF_RNG);
    float* hl   = W + OFF_HL;
    float* st   = W + OFF_ST;
    float* wT   = W + OFF_WT;

    // init + normalization stats
    init_zero<<<26, 256, 0, stream>>>(gcur, st);
    transpose_wih<<<64, 256, 0, stream>>>(w_ih, wT);
    col_sums<<<1024, 256, 0, stream>>>(x, st);
    finalize_stats<<<1, 64, 0, stream>>>(st);

    // dest-sorted CSR via two-pass counting sort (coalesced writes, no global float atomics)
    part_kernel<<<NPART, 256, 0, stream>>>(ei, ea, gcur, ent2);
    bucket_csr<<<NBUK, 256, 0, stream>>>(ent2, gcur, ent, rng, dis);

    // pre-scaled bf16 node features: xnd = bf16(dis * normalize(x))
    xnd_kernel<<<NN * 16 / 256, 256, 0, stream>>>(x, st, dis, xnd);

    // GCN layer 1, commuted: a1 = S·xn (64 cols, bf16 rows in), then g1 = a1 @ W1 (96 cols)
    gcn_gather<16><<<NN * 16 / 256, 256, 0, stream>>>(xnd, rng, ent, dis, a1);
    gemm_tiled<64, 96, 32, 192, false, false, false><<<NN / 32, 192, 0, stream>>>(
        a1, conv1_w, nullptr, nullptr, nullptr, nullptr, g1, 96);

    // GCN layer 2: h2 = bf16(dis * (relu(g1+b1) @ W2)), then g2 = S·h2
    gemm_tiled<96, 64, 64, 256, true, false, true><<<NN / 64, 256, 0, stream>>>(
        g1, conv2_w, conv1_b, nullptr, nullptr, dis, h2, 64);
    gcn_gather<16><<<NN * 16 / 256, 256, 0, stream>>>((const uint2*)h2, rng, ent, dis, g2);

    // LSTM input transform: xg = relu(g2+b2) @ w_ih^T + b_ih + b_hh
    gemm_tiled<64, 128, 32, 256, true, true, false><<<dim3(NN / 32, 2), 256, 0, stream>>>(
        g2, wT, conv2_b, b_ih, b_hh, nullptr, xg, 256);

    // LSTM recurrence: MFMA path, 16 seqs/block, 1024 threads
    lstm_kernel<<<SS / 16, 1024, 0, stream>>>(xg, w_hh, hl);

    // FC head + softmax
    head_kernel<<<SS, 128, 0, stream>>>(hl, fc1_w, fc1_b, fc2_w, fc2_b, out);
}

// Round 13
// 443.248 us; speedup vs baseline: 1.4694x; 1.0204x over previous
//
#include <hip/hip_runtime.h>
#include <hip/hip_bf16.h>
#include <hip/hip_fp16.h>

#define NN 102400      // B*T*NODES
#define DD 64
#define EE 1638400
#define L1C 96
#define L2C 64
#define TT 32
#define NODESC 400
#define BB 8
#define SS 3200        // B*NODES
#define G4 256         // 4*D

#define NBUK 400       // coarse buckets (node >> 8), NN = 400*256 exactly
#define BCAP 5120      // slots per bucket (mean 4096, sd 64 -> +16 sigma)
#define PCHUNK 8192
#define NPART (EE / PCHUNK)   // 200

// ---------------- workspace layout (floats) ----------------
// [0, 26,214,400): ent | a1 | g1  -> all dead before xg overwrites the region
#define OFF_ENT  ((size_t)0)          // NBUK*BCAP int2 = 4,096,000 floats
#define OFF_A1   ((size_t)4096000)    // NN*64 fp16 (region sized for f32; fine)
#define OFF_G1   ((size_t)10649600)   // NN*96 fp16
#define OFF_XG   ((size_t)0)          // NN*256 fp16 = 13,107,200 floats worth
#define OFF_ENT2 ((size_t)26214400)   // csr staging; then xnd bf16; then h2 bf16
#define OFF_H2   ((size_t)26214400)   // NN*64 bf16
#define OFF_G2   ((size_t)32768000)   // NN*64 fp16
#define OFF_GCUR ((size_t)39321600)   // 400 cursors padded x16 ints = 6400
#define OFF_DIS  ((size_t)39328000)   // NN -> ends 39,430,400
#define OFF_RNG  ((size_t)39430400)   // NN int2 -> ends 39,635,200
#define OFF_HL   ((size_t)39635200)   // SS*64 -> ends 39,840,000
#define OFF_ST   ((size_t)39840000)   // 256 -> ends 39,840,256
#define OFF_WT   ((size_t)39840256)   // w_ih^T [2][64][128] = 16384 -> total 39,856,640 (159.4 MB)

typedef __attribute__((ext_vector_type(8))) short s16x8;   // 8 bf16 in 4 VGPRs
typedef __attribute__((ext_vector_type(4))) float f32x4;

__device__ __forceinline__ void fma4(float4& a, float s, const float4& w) {
    a.x = fmaf(s, w.x, a.x); a.y = fmaf(s, w.y, a.y);
    a.z = fmaf(s, w.z, a.z); a.w = fmaf(s, w.w, a.w);
}
__device__ __forceinline__ float rcp_f(float x) { return __builtin_amdgcn_rcpf(x); }
__device__ __forceinline__ float sigm_f(float x) {
    x = fminf(fmaxf(x, -30.f), 30.f);
    return rcp_f(1.f + __expf(-x));
}
__device__ __forceinline__ float tanh_f(float x) {
    x = fminf(fmaxf(x, -15.f), 15.f);
    float e = __expf(2.f * x);
    return (e - 1.f) * rcp_f(e + 1.f);
}
__device__ __forceinline__ unsigned short f32_bf16_rtne(float f) {
    unsigned int u = __float_as_uint(f);
    unsigned int r = u + 0x7fffu + ((u >> 16) & 1u);
    return (unsigned short)(r >> 16);
}
__device__ __forceinline__ float bf16_f32(unsigned short h) {
    return __uint_as_float(((unsigned int)h) << 16);
}
// bf16 x4 pack/unpack (gather tables)
__device__ __forceinline__ float4 unp4(uint2 p) {
    float4 v;
    v.x = __uint_as_float(p.x << 16);
    v.y = __uint_as_float(p.x & 0xffff0000u);
    v.z = __uint_as_float(p.y << 16);
    v.w = __uint_as_float(p.y & 0xffff0000u);
    return v;
}
__device__ __forceinline__ uint2 pk4(float4 v) {
    unsigned int u0 = ((unsigned int)f32_bf16_rtne(v.y) << 16) | f32_bf16_rtne(v.x);
    unsigned int u1 = ((unsigned int)f32_bf16_rtne(v.w) << 16) | f32_bf16_rtne(v.z);
    return make_uint2(u0, u1);
}
// fp16 x4 pack/unpack (GEMM intermediates)
__device__ __forceinline__ uint2 pkh4(float4 v) {
    __half2 h0 = __floats2half2_rn(v.x, v.y);
    __half2 h1 = __floats2half2_rn(v.z, v.w);
    uint2 r;
    r.x = *(unsigned int*)&h0;
    r.y = *(unsigned int*)&h1;
    return r;
}
__device__ __forceinline__ float4 uph4(uint2 p) {
    __half2 h0 = *(__half2*)&p.x;
    __half2 h1 = *(__half2*)&p.y;
    float2 f0 = __half22float2(h0), f1 = __half22float2(h1);
    return make_float4(f0.x, f0.y, f1.x, f1.y);
}

// ---------------- init: zero bucket cursors + stats ----------------
__global__ void init_zero(int* gcur, float* st) {
    int idx = blockIdx.x * 256 + threadIdx.x;
    if (idx < NBUK * 16) gcur[idx] = 0;
    if (blockIdx.x == 0 && threadIdx.x < 128) st[threadIdx.x] = 0.f;
}

// ---------------- w_ih pre-transpose: wT[h][d][g] = w_ih[h*128+g][d] ----------------
__global__ void transpose_wih(const float* __restrict__ w_ih, float* __restrict__ wT) {
    int i = blockIdx.x * 256 + threadIdx.x;   // 0..16383
    int g = i >> 6, d = i & 63;
    float v = w_ih[i];
    int h = g >> 7, gl = g & 127;
    wT[h * 8192 + d * 128 + gl] = v;
}

// ---------------- normalization stats ----------------
__global__ __launch_bounds__(256) void col_sums(const float* __restrict__ x, float* __restrict__ st) {
    int c = threadIdx.x & 63;
    size_t i = (size_t)blockIdx.x * 256 + threadIdx.x;
    size_t stride = (size_t)gridDim.x * 256;
    float s = 0.f, q = 0.f;
    for (size_t e = i; e < (size_t)NN * 64; e += stride) {
        float v = x[e]; s += v; q = fmaf(v, v, q);
    }
    __shared__ float ls[128];
    if (threadIdx.x < 128) ls[threadIdx.x] = 0.f;
    __syncthreads();
    atomicAdd(&ls[c], s); atomicAdd(&ls[64 + c], q);
    __syncthreads();
    if (threadIdx.x < 128) atomicAdd(&st[threadIdx.x], ls[threadIdx.x]);
}

__global__ void finalize_stats(float* st) {
    int c = threadIdx.x;
    if (c < 64) {
        float s = st[c], q = st[64 + c];
        float mean = s / (float)NN;
        float var = (q - s * s / (float)NN) / (float)(NN - 1);
        st[128 + c] = mean;
        st[192 + c] = rsqrtf(fmaxf(var, 1e-20f));
    }
}

// ---------------- xnd = bf16( dis[n] * normalize(x[n]) ) ----------------
__global__ __launch_bounds__(256) void xnd_kernel(const float* __restrict__ x, const float* __restrict__ st,
                                                  const float* __restrict__ dis, uint2* __restrict__ xnd) {
    size_t i = (size_t)blockIdx.x * 256 + threadIdx.x;   // float4 index
    int n = (int)(i >> 4), q = (int)(i & 15);
    float4 v = ((const float4*)x)[i];
    float4 mean4 = ((const float4*)(st + 128))[q];
    float4 istd4 = ((const float4*)(st + 192))[q];
    float dn = dis[n];
    v.x = (v.x - mean4.x) * istd4.x * dn;
    v.y = (v.y - mean4.y) * istd4.y * dn;
    v.z = (v.z - mean4.z) * istd4.z * dn;
    v.w = (v.w - mean4.w) * istd4.w * dn;
    xnd[i] = pk4(v);
}

// ---------------- pass 1: coarse bucket partition (contiguous block-local runs) ----------------
// Entry staging format: meta = src | (dst&255)<<24 (src < 2^17), w = |ea| bits.
__global__ __launch_bounds__(256) void part_kernel(const int* __restrict__ ei, const float* __restrict__ ea,
                                                   int* __restrict__ gcur, int2* __restrict__ ent2) {
    __shared__ int lhist[NBUK];
    __shared__ int lbase[NBUK];
    const int tid = threadIdx.x;
    const int e0 = blockIdx.x * PCHUNK;
    for (int i = tid; i < NBUK; i += 256) lhist[i] = 0;
    __syncthreads();
    #pragma unroll 4
    for (int i = 0; i < PCHUNK / 256; ++i) {
        int d = ei[EE + e0 + i * 256 + tid];
        atomicAdd(&lhist[d >> 8], 1);
    }
    __syncthreads();
    // reserve one contiguous range per bucket (gcur padded: 1 counter / 64B line)
    for (int i = tid; i < NBUK; i += 256) {
        lbase[i] = atomicAdd(&gcur[i * 16], lhist[i]);
        lhist[i] = 0;
    }
    __syncthreads();
    for (int i = 0; i < PCHUNK / 256; ++i) {
        int e = e0 + i * 256 + tid;
        int d = ei[EE + e];
        int s = ei[e];
        float w = fabsf(ea[2 * (size_t)e]);
        int b = d >> 8;
        int local = atomicAdd(&lhist[b], 1);
        int pos = lbase[b] + local;
        if (pos < BCAP)
            ent2[(size_t)b * BCAP + pos] = make_int2(s | ((d & 255) << 24), __float_as_int(w));
    }
}

// ---------------- pass 2: per-bucket counting sort in LDS + rng + dis ----------------
__global__ __launch_bounds__(256) void bucket_csr(const int2* __restrict__ ent2, const int* __restrict__ gcur,
                                                  int2* __restrict__ ent, int2* __restrict__ rng,
                                                  float* __restrict__ dis) {
    __shared__ int nhist[256];
    __shared__ int scn[256];
    __shared__ float wsum[256];
    __shared__ int pcur[256];
    const int tid = threadIdx.x;
    const int b = blockIdx.x;
    const int base = b * BCAP;
    int cnt = gcur[b * 16];
    if (cnt > BCAP) cnt = BCAP;
    nhist[tid] = 0;
    wsum[tid] = 0.f;
    __syncthreads();
    for (int e = tid; e < cnt; e += 256) {
        int2 en = ent2[base + e];
        int dl = ((unsigned)en.x) >> 24;
        atomicAdd(&nhist[dl], 1);
        atomicAdd(&wsum[dl], __int_as_float(en.y));
    }
    __syncthreads();
    int c = nhist[tid];
    scn[tid] = c;
    __syncthreads();
    for (int d = 1; d < 256; d <<= 1) {
        int t = (tid >= d) ? scn[tid - d] : 0;
        __syncthreads();
        scn[tid] += t;
        __syncthreads();
    }
    int ps = scn[tid] - c;                       // exclusive prefix within bucket
    rng[b * 256 + tid] = make_int2(base + ps, base + ps + c);
    dis[b * 256 + tid] = rsqrtf(1.f + wsum[tid]); // self-loop weight 1 folded in
    pcur[tid] = ps;
    __syncthreads();
    for (int e = tid; e < cnt; e += 256) {
        int2 en = ent2[base + e];
        int dl = ((unsigned)en.x) >> 24;
        int local = atomicAdd(&pcur[dl], 1);
        ent[base + local] = make_int2(en.x & 0xFFFFFF, en.y);
    }
}

// ---------------- tiled f32 GEMM ----------------
// HIN: A rows are fp16. HOUT: C stored fp16. DISO: scale rows by dscale and
// store bf16 (feeds bf16 gather). XGOUT: permuted fp16 xg output + bias.
// ldC counts elements of the stored type.
template<int K, int NC, int MB, int THREADS, bool PRELU, bool XGOUT, bool DISO, bool HIN, bool HOUT>
__global__ __launch_bounds__(THREADS) void gemm_tiled(
    const float* __restrict__ A, const float* __restrict__ Wm,
    const float* __restrict__ bin, const float* __restrict__ bo1, const float* __restrict__ bo2,
    const float* __restrict__ dscale, float* __restrict__ Cm, int ldC)
{
    __shared__ float As[MB * K];
    __shared__ float Ws[K * NC];
    const int cb0 = XGOUT ? ((int)blockIdx.y * NC) : 0;
    const float* Wsrc = Wm + (XGOUT ? (size_t)cb0 * K : 0);

    for (int i = threadIdx.x; i < K * NC / 4; i += THREADS)
        ((float4*)Ws)[i] = ((const float4*)Wsrc)[i];

    size_t row0 = (size_t)blockIdx.x * MB;
    for (int i = threadIdx.x; i < MB * (K / 4); i += THREADS) {
        int r = i / (K / 4); int c = (i % (K / 4)) * 4;
        float4 a;
        if (HIN) {
            uint2 p = *(const uint2*)((const unsigned short*)A + (row0 + r) * K + c);
            a = uph4(p);
        } else {
            a = *(const float4*)(A + (row0 + r) * K + c);
        }
        if (PRELU) {
            a.x = fmaxf(a.x + bin[c + 0], 0.f); a.y = fmaxf(a.y + bin[c + 1], 0.f);
            a.z = fmaxf(a.z + bin[c + 2], 0.f); a.w = fmaxf(a.w + bin[c + 3], 0.f);
        }
        ((float4*)As)[i] = a;
    }
    __syncthreads();

    constexpr int NCT = NC / 4;
    int tc = threadIdx.x % NCT;
    int tr = threadIdx.x / NCT;
    int r = tr * 4;
    float4 acc[4];
    acc[0] = acc[1] = acc[2] = acc[3] = make_float4(0.f, 0.f, 0.f, 0.f);

    #pragma unroll 8
    for (int d4 = 0; d4 < K / 4; ++d4) {
        float4 w0 = ((const float4*)Ws)[(4 * d4 + 0) * NCT + tc];
        float4 w1 = ((const float4*)Ws)[(4 * d4 + 1) * NCT + tc];
        float4 w2 = ((const float4*)Ws)[(4 * d4 + 2) * NCT + tc];
        float4 w3 = ((const float4*)Ws)[(4 * d4 + 3) * NCT + tc];
        #pragma unroll
        for (int i = 0; i < 4; ++i) {
            float4 av = ((const float4*)As)[(r + i) * (K / 4) + d4];
            fma4(acc[i], av.x, w0); fma4(acc[i], av.y, w1);
            fma4(acc[i], av.z, w2); fma4(acc[i], av.w, w3);
        }
    }

    if (!XGOUT) {
        #pragma unroll
        for (int i = 0; i < 4; ++i) {
            size_t row = row0 + r + i;
            float4 o = acc[i];
            if (DISO) {
                float dn = dscale[row];
                o.x *= dn; o.y *= dn; o.z *= dn; o.w *= dn;
                *(uint2*)((unsigned short*)Cm + row * ldC + tc * 4) = pk4(o);
            } else if (HOUT) {
                *(uint2*)((unsigned short*)Cm + row * ldC + tc * 4) = pkh4(o);
            } else {
                *(float4*)(Cm + row * ldC + tc * 4) = o;
            }
        }
    } else {
        int cb = cb0 + tc * 4;
        float4 bs;
        bs.x = bo1[cb + 0] + bo2[cb + 0]; bs.y = bo1[cb + 1] + bo2[cb + 1];
        bs.z = bo1[cb + 2] + bo2[cb + 2]; bs.w = bo1[cb + 3] + bo2[cb + 3];
        #pragma unroll
        for (int i = 0; i < 4; ++i) {
            int n = (int)row0 + r + i;                      // n = b*T*NODES + t*NODES + node
            int b_ = n / (TT * NODESC);
            int rem = n - b_ * (TT * NODESC);
            int t = rem / NODESC;
            int node = rem - t * NODESC;
            int orow = (b_ * NODESC + node) * TT + t;       // seq-major, time inner
            float4 o = acc[i];
            o.x += bs.x; o.y += bs.y; o.z += bs.z; o.w += bs.w;
            *(uint2*)((unsigned short*)Cm + (size_t)orow * ldC + cb) = pkh4(o);
        }
    }
}

// ---------------- GCN aggregation: gather over packed CSR (rng int2 ranges) ----------------
// Input h rows are dis-prescaled bf16 (4 packed per uint2). Output fp16 rows
// (feeds the fp16-input GEMMs). Per edge per thread: 8B ent + random 8B row
// chunk, 8x/4x unrolled for MLP. g[n] = dis[n]*(h[n] + sum w_e*h[src]).
template<int C4>
__global__ __launch_bounds__(256) void gcn_gather(const uint2* __restrict__ h, const int2* __restrict__ rng,
                                                  const int2* __restrict__ ent, const float* __restrict__ dis,
                                                  unsigned short* __restrict__ g) {
    unsigned int idx = blockIdx.x * 256 + threadIdx.x;
    unsigned int n = idx / C4, q = idx % C4;
    float4 acc = unp4(h[(size_t)n * C4 + q]);
    int2 r = rng[n];
    int e = r.x;
    for (; e + 8 <= r.y; e += 8) {
        int2 en0 = ent[e],     en1 = ent[e + 1], en2 = ent[e + 2], en3 = ent[e + 3];
        int2 en4 = ent[e + 4], en5 = ent[e + 5], en6 = ent[e + 6], en7 = ent[e + 7];
        uint2 v0 = h[(size_t)en0.x * C4 + q];
        uint2 v1 = h[(size_t)en1.x * C4 + q];
        uint2 v2 = h[(size_t)en2.x * C4 + q];
        uint2 v3 = h[(size_t)en3.x * C4 + q];
        uint2 v4 = h[(size_t)en4.x * C4 + q];
        uint2 v5 = h[(size_t)en5.x * C4 + q];
        uint2 v6 = h[(size_t)en6.x * C4 + q];
        uint2 v7 = h[(size_t)en7.x * C4 + q];
        fma4(acc, __int_as_float(en0.y), unp4(v0));
        fma4(acc, __int_as_float(en1.y), unp4(v1));
        fma4(acc, __int_as_float(en2.y), unp4(v2));
        fma4(acc, __int_as_float(en3.y), unp4(v3));
        fma4(acc, __int_as_float(en4.y), unp4(v4));
        fma4(acc, __int_as_float(en5.y), unp4(v5));
        fma4(acc, __int_as_float(en6.y), unp4(v6));
        fma4(acc, __int_as_float(en7.y), unp4(v7));
    }
    for (; e + 4 <= r.y; e += 4) {
        int2 en0 = ent[e], en1 = ent[e + 1], en2 = ent[e + 2], en3 = ent[e + 3];
        uint2 v0 = h[(size_t)en0.x * C4 + q];
        uint2 v1 = h[(size_t)en1.x * C4 + q];
        uint2 v2 = h[(size_t)en2.x * C4 + q];
        uint2 v3 = h[(size_t)en3.x * C4 + q];
        fma4(acc, __int_as_float(en0.y), unp4(v0));
        fma4(acc, __int_as_float(en1.y), unp4(v1));
        fma4(acc, __int_as_float(en2.y), unp4(v2));
        fma4(acc, __int_as_float(en3.y), unp4(v3));
    }
    for (; e < r.y; ++e) {
        int2 en = ent[e];
        uint2 v = h[(size_t)en.x * C4 + q];
        fma4(acc, __int_as_float(en.y), unp4(v));
    }
    float dn = dis[n];
    acc.x *= dn; acc.y *= dn; acc.z *= dn; acc.w *= dn;
    *(uint2*)(g + (size_t)n * (C4 * 4) + q * 4) = pkh4(acc);
}

// ---------------- LSTM (recurrent part; xg precomputed, fp16) ----------------
// MFMA path (R8): per step, gates[16 seqs x 256 rows] = h[16x64] @ whh^T via
// mfma_f32_16x16x32_bf16 with hi/lo bf16 split (3 MFMAs, err ~2^-18).
#define HP_LD 66   // hpack row stride (uints)
#define GP_LD 257  // gp row stride (floats)

__global__ __launch_bounds__(1024, 1) void lstm_kernel(const __half* __restrict__ xg, const float* __restrict__ whh,
                                                       float* __restrict__ hlast) {
    __shared__ __align__(16) unsigned int hpack[16 * HP_LD];  // h as bf16 hi|lo
    __shared__ float gp[16 * GP_LD];                          // gate pre-activations
    const int tid  = threadIdx.x;       // 0..1023
    const int lane = tid & 63;
    const int wv   = tid >> 6;          // wave 0..15 = gate tile (dot) and seq (act)
    const int n15  = lane & 15;         // A: seq m / B: gate-in-tile n
    const int quad = lane >> 4;         // k sub-block
    const int gate = wv * 16 + n15;
    const int qa   = wv;                // activation seq 0..15
    const int ja   = lane;              // activation hidden unit 0..63

    // ---- loop-invariant B-frags: w_hh row `gate`, bf16 hi/lo split ----
    s16x8 bhi0, bhi1, blo0, blo1;
    {
        const float* wp0 = whh + (size_t)gate * 64 + 0 * 32 + quad * 8;
        const float* wp1 = whh + (size_t)gate * 64 + 1 * 32 + quad * 8;
        #pragma unroll
        for (int j = 0; j < 8; ++j) {
            float w0 = wp0[j], w1 = wp1[j];
            unsigned short h0 = f32_bf16_rtne(w0);
            unsigned short h1 = f32_bf16_rtne(w1);
            bhi0[j] = (short)h0; blo0[j] = (short)f32_bf16_rtne(w0 - bf16_f32(h0));
            bhi1[j] = (short)h1; blo1[j] = (short)f32_bf16_rtne(w1 - bf16_f32(h1));
        }
    }

    // ---- init h = 0, prefetch first xg gate inputs ----
    for (int i = tid; i < 16 * HP_LD; i += 1024) hpack[i] = 0u;
    float c_reg = 0.f, hn = 0.f;
    const __half* xa = xg + ((size_t)blockIdx.x * 16 + qa) * TT * G4 + ja;
    float xi = __half2float(xa[0]),   xf = __half2float(xa[64]);
    float xgv = __half2float(xa[128]), xo = __half2float(xa[192]);
    __syncthreads();

    for (int t = 0; t < TT; ++t) {
        // prefetch next step's gate inputs
        const int tn = (t + 1 < TT) ? t + 1 : t;
        const __half* xan = xa + tn * G4;
        float ni = __half2float(xan[0]),   nf = __half2float(xan[64]);
        float ng = __half2float(xan[128]), no = __half2float(xan[192]);

        // ---- dot phase: 6 MFMAs ----
        f32x4 c = {0.f, 0.f, 0.f, 0.f};
        #pragma unroll
        for (int kc = 0; kc < 2; ++kc) {
            const uint2* hp = (const uint2*)(hpack + n15 * HP_LD + kc * 32 + quad * 8);
            uint2 p0 = hp[0], p1 = hp[1], p2 = hp[2], p3 = hp[3];
            s16x8 ahi, alo;
            ahi[0] = (short)(p0.x & 0xffff); alo[0] = (short)(p0.x >> 16);
            ahi[1] = (short)(p0.y & 0xffff); alo[1] = (short)(p0.y >> 16);
            ahi[2] = (short)(p1.x & 0xffff); alo[2] = (short)(p1.x >> 16);
            ahi[3] = (short)(p1.y & 0xffff); alo[3] = (short)(p1.y >> 16);
            ahi[4] = (short)(p2.x & 0xffff); alo[4] = (short)(p2.x >> 16);
            ahi[5] = (short)(p2.y & 0xffff); alo[5] = (short)(p2.y >> 16);
            ahi[6] = (short)(p3.x & 0xffff); alo[6] = (short)(p3.x >> 16);
            ahi[7] = (short)(p3.y & 0xffff); alo[7] = (short)(p3.y >> 16);
            const s16x8 bh = kc ? bhi1 : bhi0;
            const s16x8 bl = kc ? blo1 : blo0;
            c = __builtin_amdgcn_mfma_f32_16x16x32_bf16(ahi, bh, c, 0, 0, 0);
            c = __builtin_amdgcn_mfma_f32_16x16x32_bf16(alo, bh, c, 0, 0, 0);
            c = __builtin_amdgcn_mfma_f32_16x16x32_bf16(ahi, bl, c, 0, 0, 0);
        }
        // C: lane holds seqs m = quad*4+r, gate column `gate`
        #pragma unroll
        for (int r = 0; r < 4; ++r)
            gp[(quad * 4 + r) * GP_LD + gate] = c[r];
        __syncthreads();

        // ---- activation phase: thread (qa, ja) ----
        {
            float gi = gp[qa * GP_LD + ja]        + xi;
            float gf = gp[qa * GP_LD + 64 + ja]   + xf;
            float gg = gp[qa * GP_LD + 128 + ja]  + xgv;
            float go = gp[qa * GP_LD + 192 + ja]  + xo;
            c_reg = sigm_f(gf) * c_reg + sigm_f(gi) * tanh_f(gg);
            hn = sigm_f(go) * tanh_f(c_reg);
            unsigned short hh = f32_bf16_rtne(hn);
            unsigned short hl = f32_bf16_rtne(hn - bf16_f32(hh));
            hpack[qa * HP_LD + ja] = (unsigned int)hh | ((unsigned int)hl << 16);
        }
        __syncthreads();
        xi = ni; xf = nf; xgv = ng; xo = no;
    }
    hlast[((size_t)blockIdx.x * 16 + qa) * 64 + ja] = hn;
}

// ---------------- FC head + softmax ----------------
__global__ __launch_bounds__(128) void head_kernel(const float* __restrict__ hl,
                                                   const float* __restrict__ w1, const float* __restrict__ b1,
                                                   const float* __restrict__ w2, const float* __restrict__ b2,
                                                   float* __restrict__ out) {
    __shared__ float hrow[64];
    __shared__ float a1[128];
    __shared__ float lg[3];
    int s = blockIdx.x, tid = threadIdx.x;
    if (tid < 64) hrow[tid] = hl[(size_t)s * 64 + tid];
    __syncthreads();
    {
        const float4* wr = (const float4*)(w1 + (size_t)tid * 64);
        const float4* hq = (const float4*)hrow;
        float4 acc = make_float4(0.f, 0.f, 0.f, 0.f);
        #pragma unroll
        for (int k = 0; k < 16; ++k) {
            float4 wv = wr[k]; float4 hv = hq[k];
            acc.x = fmaf(wv.x, hv.x, acc.x); acc.y = fmaf(wv.y, hv.y, acc.y);
            acc.z = fmaf(wv.z, hv.z, acc.z); acc.w = fmaf(wv.w, hv.w, acc.w);
        }
        a1[tid] = fmaxf((acc.x + acc.y) + (acc.z + acc.w) + b1[tid], 0.f);
    }
    __syncthreads();
    if (tid < 3) {
        const float4* wr = (const float4*)(w2 + (size_t)tid * 128);
        const float4* aq = (const float4*)a1;
        float4 acc = make_float4(0.f, 0.f, 0.f, 0.f);
        #pragma unroll
        for (int k = 0; k < 32; ++k) {
            float4 wv = wr[k]; float4 av = aq[k];
            acc.x = fmaf(wv.x, av.x, acc.x); acc.y = fmaf(wv.y, av.y, acc.y);
            acc.z = fmaf(wv.z, av.z, acc.z); acc.w = fmaf(wv.w, av.w, acc.w);
        }
        lg[tid] = (acc.x + acc.y) + (acc.z + acc.w) + b2[tid];
    }
    __syncthreads();
    if (tid == 0) {
        float m = fmaxf(lg[0], fmaxf(lg[1], lg[2]));
        float e0 = __expf(lg[0] - m), e1 = __expf(lg[1] - m), e2 = __expf(lg[2] - m);
        float inv = 1.f / (e0 + e1 + e2);
        out[(size_t)s * 3 + 0] = e0 * inv;
        out[(size_t)s * 3 + 1] = e1 * inv;
        out[(size_t)s * 3 + 2] = e2 * inv;
    }
}

extern "C" void kernel_launch(void* const* d_in, const int* in_sizes, int n_in,
                              void* d_out, int out_size, void* d_ws, size_t ws_size,
                              hipStream_t stream) {
    (void)in_sizes; (void)n_in; (void)out_size; (void)ws_size;
    const float* x        = (const float*)d_in[0];
    const float* ea       = (const float*)d_in[1];
    const float* conv1_w  = (const float*)d_in[2];
    const float* conv1_b  = (const float*)d_in[3];
    const float* conv2_w  = (const float*)d_in[4];
    const float* conv2_b  = (const float*)d_in[5];
    const float* w_ih     = (const float*)d_in[6];
    const float* w_hh     = (const float*)d_in[7];
    const float* b_ih     = (const float*)d_in[8];
    const float* b_hh     = (const float*)d_in[9];
    const float* fc1_w    = (const float*)d_in[10];
    const float* fc1_b    = (const float*)d_in[11];
    const float* fc2_w    = (const float*)d_in[12];
    const float* fc2_b    = (const float*)d_in[13];
    const int*   ei       = (const int*)d_in[14];
    float* out = (float*)d_out;

    float* W    = (float*)d_ws;
    int2*  ent  = (int2*)(W + OFF_ENT);
    unsigned short* a1h = (unsigned short*)(W + OFF_A1);   // fp16 rows
    unsigned short* g1h = (unsigned short*)(W + OFF_G1);   // fp16 rows
    unsigned short* xgh = (unsigned short*)(W + OFF_XG);   // fp16 xg
    int2*  ent2 = (int2*)(W + OFF_ENT2);
    uint2* xnd  = (uint2*)(W + OFF_ENT2);  // bf16 rows; reuses dead csr staging
    float* h2   = W + OFF_H2;              // bf16 rows; overwrites dead xnd
    unsigned short* g2h = (unsigned short*)(W + OFF_G2);   // fp16 rows
    int*   gcur = (int*)(W + OFF_GCUR);
    float* dis  = W + OFF_DIS;
    int2*  rng  = (int2*)(W + OFF_RNG);
    float* hl   = W + OFF_HL;
    float* st   = W + OFF_ST;
    float* wT   = W + OFF_WT;

    // init + normalization stats
    init_zero<<<26, 256, 0, stream>>>(gcur, st);
    transpose_wih<<<64, 256, 0, stream>>>(w_ih, wT);
    col_sums<<<1024, 256, 0, stream>>>(x, st);
    finalize_stats<<<1, 64, 0, stream>>>(st);

    // dest-sorted CSR via two-pass counting sort (coalesced writes, no global float atomics)
    part_kernel<<<NPART, 256, 0, stream>>>(ei, ea, gcur, ent2);
    bucket_csr<<<NBUK, 256, 0, stream>>>(ent2, gcur, ent, rng, dis);

    // pre-scaled bf16 node features: xnd = bf16(dis * normalize(x))
    xnd_kernel<<<NN * 16 / 256, 256, 0, stream>>>(x, st, dis, xnd);

    // GCN layer 1, commuted: a1 = S·xn (fp16 out), then g1 = a1 @ W1 (fp16 in/out)
    gcn_gather<16><<<NN * 16 / 256, 256, 0, stream>>>(xnd, rng, ent, dis, a1h);
    gemm_tiled<64, 96, 32, 192, false, false, false, true, true><<<NN / 32, 192, 0, stream>>>(
        (const float*)a1h, conv1_w, nullptr, nullptr, nullptr, nullptr, (float*)g1h, 96);

    // GCN layer 2: h2 = bf16(dis * (relu(g1+b1) @ W2)), then g2 = S·h2 (fp16 out)
    gemm_tiled<96, 64, 64, 256, true, false, true, true, false><<<NN / 64, 256, 0, stream>>>(
        (const float*)g1h, conv2_w, conv1_b, nullptr, nullptr, dis, h2, 64);
    gcn_gather<16><<<NN * 16 / 256, 256, 0, stream>>>((const uint2*)h2, rng, ent, dis, g2h);

    // LSTM input transform: xg = fp16( relu(g2+b2) @ w_ih^T + b_ih + b_hh )
    gemm_tiled<64, 128, 32, 256, true, true, false, true, true><<<dim3(NN / 32, 2), 256, 0, stream>>>(
        (const float*)g2h, wT, conv2_b, b_ih, b_hh, nullptr, (float*)xgh, 256);

    // LSTM recurrence: MFMA path, 16 seqs/block, 1024 threads (fp16 xg in)
    lstm_kernel<<<SS / 16, 1024, 0, stream>>>((const __half*)xgh, w_hh, hl);

    // FC head + softmax
    head_kernel<<<SS, 128, 0, stream>>>(hl, fc1_w, fc1_b, fc2_w, fc2_b, out);
}